// Round 12
// baseline (125.807 us; speedup 1.0000x reference)
//
#include <hip/hip_runtime.h>
#include <hip/hip_bf16.h>
#include <math.h>

#define D_CH   256
#define NHEAD  4
#define DHEAD  64
#define NPTS   4096
#define KSPLIT 8
#define KCHUNK (NPTS / KSPLIT)          // 512 keys = 8 tiles of 64
#define BN_RSQ 0.99999500003749963f     // 1/sqrt(1 + 1e-5)
#define HSTRIDE 262144                  // 4096*64 ushorts per head
#define QSCALE 0.18033688011112042f     // 0.125 * log2(e)  (exp2 folding)

typedef __attribute__((ext_vector_type(4))) float f32x4;
typedef __attribute__((ext_vector_type(8))) short bf16x8;
typedef unsigned short ushort_t;

__device__ __forceinline__ ushort_t f2bf(float x) {
    unsigned int b = __float_as_uint(x);
    return (ushort_t)((b + 0x7FFF + ((b >> 16) & 1)) >> 16);  // RNE
}
__device__ __forceinline__ float bf2f(ushort_t u) {
    return __uint_as_float(((unsigned int)u) << 16);
}
__device__ __forceinline__ unsigned pack2bf(float lo, float hi) {
    return (unsigned)f2bf(lo) | ((unsigned)f2bf(hi) << 16);
}

// ---------------------------------------------------------------------------
// prep: transpose-cast x [256][4096] f32 -> xT [4096][256] bf16
// ---------------------------------------------------------------------------
__global__ __launch_bounds__(256) void transpose_cast(
    const float* __restrict__ x, ushort_t* __restrict__ xT)
{
    __shared__ float xs[64][65];
    const int tid = threadIdx.x;
    const int n0 = blockIdx.x * 64, k0 = blockIdx.y * 64;
#pragma unroll
    for (int p = 0; p < 16; ++p) {
        int kk = p * 4 + (tid >> 6), nn = tid & 63;
        xs[kk][nn] = x[(size_t)(k0 + kk) * NPTS + n0 + nn];
    }
    __syncthreads();
#pragma unroll
    for (int p = 0; p < 16; ++p) {
        int nn = p * 4 + (tid >> 6), kk = tid & 63;
        xT[(size_t)(n0 + nn) * D_CH + k0 + kk] = f2bf(xs[kk][nn]);
    }
}

// ---------------------------------------------------------------------------
// prep: S [4096][4096] f32 -> Sf16 bf16 fragment layout (32 MB):
//   Sf16[(qt*64+kt)*4096 + w*1024 + lane*16 + kb*4 + r]
//     = S[qt*64 + w*16 + (lane&15)][kt*64 + kb*16 + (lane>>4)*4 + r]
// Per-lane 32B contiguous; both global sides coalesced.
// ---------------------------------------------------------------------------
__global__ __launch_bounds__(256) void prep_mask(
    const float* __restrict__ S, ushort_t* __restrict__ Sf16)
{
    __shared__ float lds[64][68];
    const int tid = threadIdx.x;
    const int qt = blockIdx.x, kt = blockIdx.y;
    const float* Sblk = S + (size_t)qt * 64 * NPTS + kt * 64;

#pragma unroll
    for (int p = 0; p < 4; ++p) {
        int slot = p * 256 + tid;
        int row = slot >> 4, col4 = slot & 15;
        f32x4 v = *(const f32x4*)&Sblk[(size_t)row * NPTS + col4 * 4];
        *(f32x4*)&lds[row][col4 * 4] = v;
    }
    __syncthreads();

    const int w = tid >> 6, lane = tid & 63;
    const int q = w * 16 + (lane & 15);
    const int lhi = lane >> 4;
    unsigned out8[8];
#pragma unroll
    for (int jq = 0; jq < 4; ++jq) {
        f32x4 v = *(const f32x4*)&lds[q][jq * 16 + lhi * 4];
        out8[jq * 2]     = pack2bf(v.x, v.y);
        out8[jq * 2 + 1] = pack2bf(v.z, v.w);
    }
    unsigned* dst = (unsigned*)Sf16 + ((size_t)qt * 64 + kt) * 2048 + tid * 8;
    *(uint4*)dst       = make_uint4(out8[0], out8[1], out8[2], out8[3]);
    *(uint4*)(dst + 4) = make_uint4(out8[4], out8[5], out8[6], out8[7]);
}

// ---------------------------------------------------------------------------
// Shared MFMA GEMM tile body: acc[2][2] = sum_k A[m][k]*Bt[n][k]
// ---------------------------------------------------------------------------
__device__ __forceinline__ void gemm_tile_body(
    const float* __restrict__ A, const ushort_t* __restrict__ Bt,
    int K, int m0, int n0, int l15, int lhi, f32x4 acc[2][2])
{
#pragma unroll
    for (int i = 0; i < 2; ++i)
#pragma unroll
        for (int j = 0; j < 2; ++j) acc[i][j] = (f32x4){0.f, 0.f, 0.f, 0.f};

    for (int k0 = 0; k0 < K; k0 += 32) {
        bf16x8 af[2], bfr[2];
#pragma unroll
        for (int mf = 0; mf < 2; ++mf) {
            const float* ap = A + (size_t)(m0 + mf * 16 + l15) * K + k0 + lhi * 8;
            float4 a0 = *(const float4*)ap;
            float4 a1 = *(const float4*)(ap + 4);
            bf16x8 t;
            t[0] = (short)f2bf(a0.x); t[1] = (short)f2bf(a0.y);
            t[2] = (short)f2bf(a0.z); t[3] = (short)f2bf(a0.w);
            t[4] = (short)f2bf(a1.x); t[5] = (short)f2bf(a1.y);
            t[6] = (short)f2bf(a1.z); t[7] = (short)f2bf(a1.w);
            af[mf] = t;
        }
#pragma unroll
        for (int nf = 0; nf < 2; ++nf)
            bfr[nf] = *(const bf16x8*)&Bt[(size_t)(n0 + nf * 16 + l15) * K + k0 + lhi * 8];
#pragma unroll
        for (int mf = 0; mf < 2; ++mf)
#pragma unroll
            for (int nf = 0; nf < 2; ++nf)
                acc[mf][nf] = __builtin_amdgcn_mfma_f32_16x16x32_bf16(af[mf], bfr[nf], acc[mf][nf], 0, 0, 0);
    }
}

// ---------------------------------------------------------------------------
// Fused QKV projection -> fragment-major layouts.
// Q gets 0.125*log2(e) folded in (exp2 trick).
// ---------------------------------------------------------------------------
__global__ __launch_bounds__(256) void gemm_qkv(
    const float* __restrict__ Wq, const float* __restrict__ bq,
    const float* __restrict__ Wk, const float* __restrict__ bk,
    const float* __restrict__ Wv, const float* __restrict__ bv,
    const ushort_t* __restrict__ xT,
    ushort_t* __restrict__ Qf, ushort_t* __restrict__ Kf, ushort_t* __restrict__ Vf)
{
    const int tid = threadIdx.x;
    const int w = tid >> 6, lane = tid & 63, l15 = lane & 15, lhi = lane >> 4;
    const int wm = w >> 1, wn = w & 1;
    const int m0 = blockIdx.y * 64 + wm * 32;
    const int n0 = blockIdx.x * 64 + wn * 32;
    const int z = blockIdx.z;

    const float* A    = (z == 0) ? Wq : (z == 1) ? Wk : Wv;
    const float* bias = (z == 0) ? bq : (z == 1) ? bk : bv;
    ushort_t* dst     = (z == 0) ? Qf : (z == 1) ? Kf : Vf;
    const float scl   = (z == 0) ? QSCALE : 1.0f;

    f32x4 acc[2][2];
    gemm_tile_body(A, xT, D_CH, m0, n0, l15, lhi, acc);

#pragma unroll
    for (int mf = 0; mf < 2; ++mf) {
#pragma unroll
        for (int r = 0; r < 4; ++r) {
            int m = m0 + mf * 16 + lhi * 4 + r;
            int head = m >> 6, dch = m & 63;
            float bi = bias[m];
#pragma unroll
            for (int nf = 0; nf < 2; ++nf) {
                int n = n0 + nf * 16 + l15;
                float v = (acc[mf][nf][r] + bi) * scl;
                size_t idx;
                if (z < 2)
                    idx = (size_t)head * HSTRIDE + (size_t)(n >> 4) * 1024 + (dch >> 5) * 512
                        + (((dch >> 3) & 3) * 16 + (n & 15)) * 8 + (dch & 7);
                else
                    idx = (size_t)head * HSTRIDE + (size_t)(n >> 6) * 4096 + (dch >> 4) * 1024
                        + ((n >> 5) & 1) * 512 + (((n >> 3) & 3) * 16 + (dch & 15)) * 8 + (n & 7);
                dst[idx] = f2bf(v);
            }
        }
    }
}

// ---------------------------------------------------------------------------
// Small-tile MFMA GEMM for the MLP chain: block tile 32(M) x 64(N).
// out_mode: 0 = f32 C[m][n] (+resid);  3 = bf16 transposed Cu[n*M + m]
// ---------------------------------------------------------------------------
__global__ __launch_bounds__(256) void gemm_mfma32(
    const float* __restrict__ A, const ushort_t* __restrict__ Bt,
    void* __restrict__ Cout, int M, int N, int K,
    const float* __restrict__ bias, const float* __restrict__ gamma,
    const float* __restrict__ beta, int relu, const float* __restrict__ resid,
    int out_mode)
{
    const int tid = threadIdx.x;
    const int w = tid >> 6, lane = tid & 63, l15 = lane & 15, lhi = lane >> 4;
    const int wm = w >> 1, wn = w & 1;
    const int m0 = blockIdx.y * 32 + wm * 16;
    const int n0 = blockIdx.x * 64 + wn * 32;

    f32x4 acc[2];
#pragma unroll
    for (int j = 0; j < 2; ++j) acc[j] = (f32x4){0.f, 0.f, 0.f, 0.f};

    for (int k0 = 0; k0 < K; k0 += 32) {
        const float* ap = A + (size_t)(m0 + l15) * K + k0 + lhi * 8;
        float4 a0 = *(const float4*)ap;
        float4 a1 = *(const float4*)(ap + 4);
        bf16x8 af;
        af[0] = (short)f2bf(a0.x); af[1] = (short)f2bf(a0.y);
        af[2] = (short)f2bf(a0.z); af[3] = (short)f2bf(a0.w);
        af[4] = (short)f2bf(a1.x); af[5] = (short)f2bf(a1.y);
        af[6] = (short)f2bf(a1.z); af[7] = (short)f2bf(a1.w);
#pragma unroll
        for (int nf = 0; nf < 2; ++nf) {
            bf16x8 bfr = *(const bf16x8*)&Bt[(size_t)(n0 + nf * 16 + l15) * K + k0 + lhi * 8];
            acc[nf] = __builtin_amdgcn_mfma_f32_16x16x32_bf16(af, bfr, acc[nf], 0, 0, 0);
        }
    }

    float* Cf = (float*)Cout;
    ushort_t* Cu = (ushort_t*)Cout;
#pragma unroll
    for (int r = 0; r < 4; ++r) {
        int m = m0 + lhi * 4 + r;
        float bi = bias[m];
        float sc = 1.0f, sh = 0.0f;
        if (gamma) { sc = gamma[m] * BN_RSQ; sh = beta[m]; }
#pragma unroll
        for (int nf = 0; nf < 2; ++nf) {
            int n = n0 + nf * 16 + l15;
            float v = acc[nf][r] + bi;
            if (gamma) v = v * sc + sh;
            if (relu)  v = fmaxf(v, 0.0f);
            if (resid) v += resid[(size_t)m * N + n];
            if (out_mode == 0) Cf[(size_t)m * N + n] = v;
            else               Cu[(size_t)n * M + m] = f2bf(v);
        }
    }
}

// ---------------------------------------------------------------------------
// One 64-key tile, no-max softmax (p = exp2(s'*m), log2e pre-folded in Q).
// sbuf holds THIS tile's bf16 mask; after renaming it out, the SAME register
// pair is refilled with tile ktp's mask (distance-2 prefetch: the vmcnt wait
// lands two tiles later).
// ---------------------------------------------------------------------------
__device__ __forceinline__ void attn_tile(
    int kt, int ktp, const ushort_t* __restrict__ Sfw,
    const ushort_t* __restrict__ Kh, const ushort_t* __restrict__ Vh,
    const bf16x8& qf0, const bf16x8& qf1,
    bf16x8 (&sbuf)[2],
    f32x4 (&macc)[4], float& lrun,
    ushort_t (* __restrict__ Pw)[72], int l15, int lhi, int lane)
{
    // rename current mask out of the buffer, then refill (SSA: no real copy)
    bf16x8 mcur0 = sbuf[0], mcur1 = sbuf[1];
    sbuf[0] = *(const bf16x8*)&Sfw[(size_t)ktp * 4096];
    sbuf[1] = *(const bf16x8*)&Sfw[(size_t)ktp * 4096 + 8];

    // QK^T swapped: sacc[kb][r] = score[key=kb*16+lhi*4+r][q=l15]
    f32x4 sacc[4];
#pragma unroll
    for (int kb = 0; kb < 4; ++kb) {
        const ushort_t* kp = Kh + (size_t)(kt * 4 + kb) * 1024 + lane * 8;
        bf16x8 kf0 = *(const bf16x8*)kp;
        bf16x8 kf1 = *(const bf16x8*)(kp + 512);
        f32x4 z = (f32x4){0.f, 0.f, 0.f, 0.f};
        z = __builtin_amdgcn_mfma_f32_16x16x32_bf16(kf0, qf0, z, 0, 0, 0);
        z = __builtin_amdgcn_mfma_f32_16x16x32_bf16(kf1, qf1, z, 0, 0, 0);
        sacc[kb] = z;
    }

    // issue V loads; exp + LDS round-trip covers their latency
    bf16x8 vf[8];
    const ushort_t* vb = Vh + (size_t)kt * 4096 + lane * 8;
#pragma unroll
    for (int mm = 0; mm < 2; ++mm)
#pragma unroll
        for (int db = 0; db < 4; ++db)
            vf[mm * 4 + db] = *(const bf16x8*)(vb + db * 1024 + mm * 512);

    // p = exp2(score * mask); accumulate l; pack -> P_lds, fused per kb
    float ts = 0.0f;
#pragma unroll
    for (int kb = 0; kb < 4; ++kb) {
        const bf16x8& mc = (kb < 2) ? mcur0 : mcur1;
        const int jb = (kb & 1) * 4;
        float p0 = exp2f(sacc[kb][0] * bf2f((ushort_t)mc[jb]));
        float p1 = exp2f(sacc[kb][1] * bf2f((ushort_t)mc[jb + 1]));
        float p2 = exp2f(sacc[kb][2] * bf2f((ushort_t)mc[jb + 2]));
        float p3 = exp2f(sacc[kb][3] * bf2f((ushort_t)mc[jb + 3]));
        ts += (p0 + p1) + (p2 + p3);
        *(unsigned*)&Pw[l15][kb * 16 + lhi * 4]     = pack2bf(p0, p1);
        *(unsigned*)&Pw[l15][kb * 16 + lhi * 4 + 2] = pack2bf(p2, p3);
    }
    lrun += ts;
    // same-wave RAW through LDS; compiler inserts lgkmcnt wait

    // PV: mfma(A=V row=d, B=P col=q)
#pragma unroll
    for (int mm = 0; mm < 2; ++mm) {
        bf16x8 pf = *(const bf16x8*)&Pw[l15][mm * 32 + lhi * 8];
#pragma unroll
        for (int db = 0; db < 4; ++db)
            macc[db] = __builtin_amdgcn_mfma_f32_16x16x32_bf16(vf[mm * 4 + db], pf, macc[db], 0, 0, 0);
    }
}

// ---------------------------------------------------------------------------
// MFMA flash attention: per-head blocks, key-split 8, fragment-major inputs,
// distance-2 register S pipeline, no-max exp2 softmax.
// ---------------------------------------------------------------------------
__global__ __launch_bounds__(256, 4) void attn_mfma(
    const ushort_t* __restrict__ Qf, const ushort_t* __restrict__ Kf,
    const ushort_t* __restrict__ Vf, const ushort_t* __restrict__ Sf16,
    ushort_t* __restrict__ pacc, float* __restrict__ pl)
{
    __shared__ __align__(16) ushort_t P_lds[4][16][72];   // 9216 B

    const int tid  = threadIdx.x;
    const int w    = tid >> 6;
    const int lane = tid & 63;
    const int l15  = lane & 15;
    const int lhi  = lane >> 4;
    const int h    = blockIdx.y;
    const int ks   = blockIdx.z;
    const int q0   = blockIdx.x * 64 + w * 16;
    const int ktb  = ks * (KCHUNK / 64);

    const ushort_t* Kh = Kf + (size_t)h * HSTRIDE;
    const ushort_t* Vh = Vf + (size_t)h * HSTRIDE;
    const ushort_t* Sfw = Sf16 + (size_t)blockIdx.x * 64 * 4096 + w * 1024 + lane * 16;
    ushort_t (* __restrict__ Pw)[72] = P_lds[w];

    bf16x8 qf0, qf1;
    {
        const ushort_t* qp = Qf + (size_t)h * HSTRIDE + (size_t)(q0 >> 4) * 1024 + lane * 8;
        qf0 = *(const bf16x8*)qp;
        qf1 = *(const bf16x8*)(qp + 512);
    }

    f32x4 macc[4];
#pragma unroll
    for (int db = 0; db < 4; ++db) macc[db] = (f32x4){0.f, 0.f, 0.f, 0.f};
    float lrun = 0.0f;

    // prologue: mask tiles ktb, ktb+1 into the two register buffers
    bf16x8 sA[2], sB[2];
    sA[0] = *(const bf16x8*)&Sfw[(size_t)ktb * 4096];
    sA[1] = *(const bf16x8*)&Sfw[(size_t)ktb * 4096 + 8];
    sB[0] = *(const bf16x8*)&Sfw[(size_t)(ktb + 1) * 4096];
    sB[1] = *(const bf16x8*)&Sfw[(size_t)(ktb + 1) * 4096 + 8];

    // 8 tiles -> 4 pair-iterations; prefetch distance 2 (wrap harmless)
    for (int kt = ktb; kt < ktb + 8; kt += 2) {
        const int kp0 = (kt + 2 < ktb + 8) ? kt + 2 : ktb;
        const int kp1 = (kt + 3 < ktb + 8) ? kt + 3 : ktb;
        attn_tile(kt,     kp0, Sfw, Kh, Vh, qf0, qf1, sA, macc, lrun, Pw, l15, lhi, lane);
        attn_tile(kt + 1, kp1, Sfw, Kh, Vh, qf0, qf1, sB, macc, lrun, Pw, l15, lhi, lane);
    }

    // deferred cross-group l reduction (once per block)
    lrun += __shfl_xor(lrun, 16);
    lrun += __shfl_xor(lrun, 32);

    // store unnormalized partials
    const size_t pb = ((size_t)ks * NHEAD + h) * NPTS;
    ushort_t* prow = pacc + (pb + q0 + l15) * DHEAD;
#pragma unroll
    for (int db = 0; db < 4; ++db) {
        *(unsigned*)&prow[db * 16 + lhi * 4]     = pack2bf(macc[db][0], macc[db][1]);
        *(unsigned*)&prow[db * 16 + lhi * 4 + 2] = pack2bf(macc[db][2], macc[db][3]);
    }
    if (lane < 16) pl[pb + q0 + lane] = lrun;
}

// ---------------------------------------------------------------------------
// Merge KSPLIT partials (common scale) -> msgT [N][256] bf16.
// ---------------------------------------------------------------------------
__global__ __launch_bounds__(256) void attn_merge(
    const ushort_t* __restrict__ pacc, const float* __restrict__ pl,
    ushort_t* __restrict__ msgT)
{
    const int h = blockIdx.y;
    const int q = blockIdx.x * 64 + (threadIdx.x >> 2);
    const int d0 = (threadIdx.x & 3) * 16;

    float ls = 0.0f;
#pragma unroll
    for (int ks = 0; ks < KSPLIT; ++ks)
        ls += pl[((size_t)ks * NHEAD + h) * NPTS + q];
    float inv = 1.0f / ls;

    float out[16];
#pragma unroll
    for (int j = 0; j < 16; ++j) out[j] = 0.0f;
#pragma unroll
    for (int ks = 0; ks < KSPLIT; ++ks) {
        const ushort_t* ap = pacc + (((size_t)ks * NHEAD + h) * NPTS + q) * DHEAD + d0;
        bf16x8 v0 = *(const bf16x8*)ap;
        bf16x8 v1 = *(const bf16x8*)(ap + 8);
#pragma unroll
        for (int j = 0; j < 8; ++j) {
            out[j]     += bf2f((ushort_t)v0[j]);
            out[8 + j] += bf2f((ushort_t)v1[j]);
        }
    }
    bf16x8 o0, o1;
#pragma unroll
    for (int j = 0; j < 8; ++j) {
        o0[j] = (short)f2bf(out[j] * inv);
        o1[j] = (short)f2bf(out[8 + j] * inv);
    }
    ushort_t* op = msgT + (size_t)q * D_CH + h * DHEAD + d0;
    *(bf16x8*)op = o0;
    *(bf16x8*)(op + 8) = o1;
}

// ---------------------------------------------------------------------------
extern "C" void kernel_launch(void* const* d_in, const int* in_sizes, int n_in,
                              void* d_out, int out_size, void* d_ws, size_t ws_size,
                              hipStream_t stream) {
    const float* x  = (const float*)d_in[0];
    const float* S  = (const float*)d_in[1];
    const float* Wq = (const float*)d_in[2];
    const float* bq = (const float*)d_in[3];
    const float* Wk = (const float*)d_in[4];
    const float* bk = (const float*)d_in[5];
    const float* Wv = (const float*)d_in[6];
    const float* bv = (const float*)d_in[7];
    const float* W1 = (const float*)d_in[8];
    const float* b1 = (const float*)d_in[9];
    const float* g1 = (const float*)d_in[10];
    const float* be1= (const float*)d_in[11];
    const float* W2 = (const float*)d_in[12];
    const float* b2 = (const float*)d_in[13];
    const float* g2 = (const float*)d_in[14];
    const float* be2= (const float*)d_in[15];
    const float* W3 = (const float*)d_in[16];
    const float* b3 = (const float*)d_in[17];

    char* ws = (char*)d_ws;
    const size_t MB = 1024 * 1024;
    // Sf16 occupies 0..32MB; xT (dead after gemm_qkv) overlaps its head.
    ushort_t* Sf16 = (ushort_t*)(ws);                        // 32 MB bf16 fragment mask
    ushort_t* xT   = (ushort_t*)(ws);                        // 2 MB (consumed before prep_mask)
    ushort_t* Qf   = (ushort_t*)(ws + 32 * MB);              // 2 MB
    ushort_t* Kf   = (ushort_t*)(ws + 34 * MB);              // 2 MB
    ushort_t* Vf   = (ushort_t*)(ws + 36 * MB);              // 2 MB
    ushort_t* pacc = (ushort_t*)(ws + 38 * MB);              // 16 MB
    float*    pl   = (float*)   (ws + 54 * MB);              // 512 KB
    ushort_t* msgT = (ushort_t*)(ws + 55 * MB);              // 2 MB
    ushort_t* h1T  = (ushort_t*)(ws + 57 * MB);              // 1 MB
    ushort_t* h2T  = (ushort_t*)(ws + 58 * MB);              // 1 MB

    transpose_cast<<<dim3(64, 4), 256, 0, stream>>>(x, xT);
    gemm_qkv<<<dim3(64, 4, 3), 256, 0, stream>>>(Wq, bq, Wk, bk, Wv, bv, xT, Qf, Kf, Vf);
    prep_mask<<<dim3(64, 64), 256, 0, stream>>>(S, Sf16);

    attn_mfma<<<dim3(64, NHEAD, KSPLIT), 256, 0, stream>>>(Qf, Kf, Vf, Sf16, pacc, pl);
    attn_merge<<<dim3(64, NHEAD), 256, 0, stream>>>(pacc, pl, msgT);

    gemm_mfma32<<<dim3(64, 4), 256, 0, stream>>>(W1, msgT, h1T, 128, NPTS, 256, b1, g1, be1, 1, nullptr, 3);
    gemm_mfma32<<<dim3(64, 4), 256, 0, stream>>>(W2, h1T, h2T, 128, NPTS, 128, b2, g2, be2, 1, nullptr, 3);
    gemm_mfma32<<<dim3(64, 8), 256, 0, stream>>>(W3, h2T, d_out, 256, NPTS, 128, b3, nullptr, nullptr, 0, x, 0);
}

// Round 13
// 108.700 us; speedup vs baseline: 1.1574x; 1.1574x over previous
//
#include <hip/hip_runtime.h>
#include <hip/hip_bf16.h>
#include <math.h>

#define D_CH   256
#define NHEAD  4
#define DHEAD  64
#define NPTS   4096
#define KSPLIT 8
#define KCHUNK (NPTS / KSPLIT)          // 512 keys = 8 tiles of 64
#define BN_RSQ 0.99999500003749963f     // 1/sqrt(1 + 1e-5)
#define HSTRIDE 262144                  // 4096*64 ushorts per head

typedef __attribute__((ext_vector_type(4))) float f32x4;
typedef __attribute__((ext_vector_type(8))) short bf16x8;
typedef unsigned short ushort_t;

__device__ __forceinline__ ushort_t f2bf(float x) {
    unsigned int b = __float_as_uint(x);
    return (ushort_t)((b + 0x7FFF + ((b >> 16) & 1)) >> 16);  // RNE
}
__device__ __forceinline__ float bf2f(ushort_t u) {
    return __uint_as_float(((unsigned int)u) << 16);
}
__device__ __forceinline__ unsigned pack2bf(float lo, float hi) {
    return (unsigned)f2bf(lo) | ((unsigned)f2bf(hi) << 16);
}

// ---------------------------------------------------------------------------
// prep: transpose-cast x [256][4096] f32 -> xT [4096][256] bf16
// ---------------------------------------------------------------------------
__global__ __launch_bounds__(256) void transpose_cast(
    const float* __restrict__ x, ushort_t* __restrict__ xT)
{
    __shared__ float xs[64][65];
    const int tid = threadIdx.x;
    const int n0 = blockIdx.x * 64, k0 = blockIdx.y * 64;
#pragma unroll
    for (int p = 0; p < 16; ++p) {
        int kk = p * 4 + (tid >> 6), nn = tid & 63;
        xs[kk][nn] = x[(size_t)(k0 + kk) * NPTS + n0 + nn];
    }
    __syncthreads();
#pragma unroll
    for (int p = 0; p < 16; ++p) {
        int nn = p * 4 + (tid >> 6), kk = tid & 63;
        xT[(size_t)(n0 + nn) * D_CH + k0 + kk] = f2bf(xs[kk][nn]);
    }
}

// ---------------------------------------------------------------------------
// Shared MFMA GEMM tile body: acc[2][2] = sum_k A[m][k]*Bt[n][k]
// ---------------------------------------------------------------------------
__device__ __forceinline__ void gemm_tile_body(
    const float* __restrict__ A, const ushort_t* __restrict__ Bt,
    int K, int m0, int n0, int l15, int lhi, f32x4 acc[2][2])
{
#pragma unroll
    for (int i = 0; i < 2; ++i)
#pragma unroll
        for (int j = 0; j < 2; ++j) acc[i][j] = (f32x4){0.f, 0.f, 0.f, 0.f};

    for (int k0 = 0; k0 < K; k0 += 32) {
        bf16x8 af[2], bfr[2];
#pragma unroll
        for (int mf = 0; mf < 2; ++mf) {
            const float* ap = A + (size_t)(m0 + mf * 16 + l15) * K + k0 + lhi * 8;
            float4 a0 = *(const float4*)ap;
            float4 a1 = *(const float4*)(ap + 4);
            bf16x8 t;
            t[0] = (short)f2bf(a0.x); t[1] = (short)f2bf(a0.y);
            t[2] = (short)f2bf(a0.z); t[3] = (short)f2bf(a0.w);
            t[4] = (short)f2bf(a1.x); t[5] = (short)f2bf(a1.y);
            t[6] = (short)f2bf(a1.z); t[7] = (short)f2bf(a1.w);
            af[mf] = t;
        }
#pragma unroll
        for (int nf = 0; nf < 2; ++nf)
            bfr[nf] = *(const bf16x8*)&Bt[(size_t)(n0 + nf * 16 + l15) * K + k0 + lhi * 8];
#pragma unroll
        for (int mf = 0; mf < 2; ++mf)
#pragma unroll
            for (int nf = 0; nf < 2; ++nf)
                acc[mf][nf] = __builtin_amdgcn_mfma_f32_16x16x32_bf16(af[mf], bfr[nf], acc[mf][nf], 0, 0, 0);
    }
}

// ---------------------------------------------------------------------------
// Fused QKV projection -> fragment-major layouts (0.125 folded into Q).
// ---------------------------------------------------------------------------
__global__ __launch_bounds__(256) void gemm_qkv(
    const float* __restrict__ Wq, const float* __restrict__ bq,
    const float* __restrict__ Wk, const float* __restrict__ bk,
    const float* __restrict__ Wv, const float* __restrict__ bv,
    const ushort_t* __restrict__ xT,
    ushort_t* __restrict__ Qf, ushort_t* __restrict__ Kf, ushort_t* __restrict__ Vf)
{
    const int tid = threadIdx.x;
    const int w = tid >> 6, lane = tid & 63, l15 = lane & 15, lhi = lane >> 4;
    const int wm = w >> 1, wn = w & 1;
    const int m0 = blockIdx.y * 64 + wm * 32;
    const int n0 = blockIdx.x * 64 + wn * 32;
    const int z = blockIdx.z;

    const float* A    = (z == 0) ? Wq : (z == 1) ? Wk : Wv;
    const float* bias = (z == 0) ? bq : (z == 1) ? bk : bv;
    ushort_t* dst     = (z == 0) ? Qf : (z == 1) ? Kf : Vf;
    const float scl   = (z == 0) ? 0.125f : 1.0f;

    f32x4 acc[2][2];
    gemm_tile_body(A, xT, D_CH, m0, n0, l15, lhi, acc);

#pragma unroll
    for (int mf = 0; mf < 2; ++mf) {
#pragma unroll
        for (int r = 0; r < 4; ++r) {
            int m = m0 + mf * 16 + lhi * 4 + r;
            int head = m >> 6, dch = m & 63;
            float bi = bias[m];
#pragma unroll
            for (int nf = 0; nf < 2; ++nf) {
                int n = n0 + nf * 16 + l15;
                float v = (acc[mf][nf][r] + bi) * scl;
                size_t idx;
                if (z < 2)
                    idx = (size_t)head * HSTRIDE + (size_t)(n >> 4) * 1024 + (dch >> 5) * 512
                        + (((dch >> 3) & 3) * 16 + (n & 15)) * 8 + (dch & 7);
                else
                    idx = (size_t)head * HSTRIDE + (size_t)(n >> 6) * 4096 + (dch >> 4) * 1024
                        + ((n >> 5) & 1) * 512 + (((n >> 3) & 3) * 16 + (dch & 15)) * 8 + (n & 7);
                dst[idx] = f2bf(v);
            }
        }
    }
}

// ---------------------------------------------------------------------------
// Small-tile MFMA GEMM for the MLP chain: block tile 32(M) x 64(N).
// out_mode: 0 = f32 C[m][n] (+resid);  3 = bf16 transposed Cu[n*M + m]
// ---------------------------------------------------------------------------
__global__ __launch_bounds__(256) void gemm_mfma32(
    const float* __restrict__ A, const ushort_t* __restrict__ Bt,
    void* __restrict__ Cout, int M, int N, int K,
    const float* __restrict__ bias, const float* __restrict__ gamma,
    const float* __restrict__ beta, int relu, const float* __restrict__ resid,
    int out_mode)
{
    const int tid = threadIdx.x;
    const int w = tid >> 6, lane = tid & 63, l15 = lane & 15, lhi = lane >> 4;
    const int wm = w >> 1, wn = w & 1;
    const int m0 = blockIdx.y * 32 + wm * 16;
    const int n0 = blockIdx.x * 64 + wn * 32;

    f32x4 acc[2];
#pragma unroll
    for (int j = 0; j < 2; ++j) acc[j] = (f32x4){0.f, 0.f, 0.f, 0.f};

    for (int k0 = 0; k0 < K; k0 += 32) {
        const float* ap = A + (size_t)(m0 + l15) * K + k0 + lhi * 8;
        float4 a0 = *(const float4*)ap;
        float4 a1 = *(const float4*)(ap + 4);
        bf16x8 af;
        af[0] = (short)f2bf(a0.x); af[1] = (short)f2bf(a0.y);
        af[2] = (short)f2bf(a0.z); af[3] = (short)f2bf(a0.w);
        af[4] = (short)f2bf(a1.x); af[5] = (short)f2bf(a1.y);
        af[6] = (short)f2bf(a1.z); af[7] = (short)f2bf(a1.w);
#pragma unroll
        for (int nf = 0; nf < 2; ++nf) {
            bf16x8 bfr = *(const bf16x8*)&Bt[(size_t)(n0 + nf * 16 + l15) * K + k0 + lhi * 8];
            acc[nf] = __builtin_amdgcn_mfma_f32_16x16x32_bf16(af, bfr, acc[nf], 0, 0, 0);
        }
    }

    float* Cf = (float*)Cout;
    ushort_t* Cu = (ushort_t*)Cout;
#pragma unroll
    for (int r = 0; r < 4; ++r) {
        int m = m0 + lhi * 4 + r;
        float bi = bias[m];
        float sc = 1.0f, sh = 0.0f;
        if (gamma) { sc = gamma[m] * BN_RSQ; sh = beta[m]; }
#pragma unroll
        for (int nf = 0; nf < 2; ++nf) {
            int n = n0 + nf * 16 + l15;
            float v = acc[nf][r] + bi;
            if (gamma) v = v * sc + sh;
            if (relu)  v = fmaxf(v, 0.0f);
            if (resid) v += resid[(size_t)m * N + n];
            if (out_mode == 0) Cf[(size_t)m * N + n] = v;
            else               Cu[(size_t)n * M + m] = f2bf(v);
        }
    }
}

// ---------------------------------------------------------------------------
// One 64-key tile, NON-swapped QK (mfma(Q,K): score row=q=lhi*4+r,
// col=key=kb*16+l15). The mask for this layout comes straight from
// row-major S with a 4-segment-per-instruction pattern — registers only,
// no prep kernel, no LDS staging. No-max softmax (bounded scores).
//   scur[r][kb] = S[q0+lhi*4+r][kt*64+kb*16+l15]  (loaded one tile ahead)
// ---------------------------------------------------------------------------
__device__ __forceinline__ void attn_tile(
    int kt, int ktn, const float* __restrict__ Sgw,
    const ushort_t* __restrict__ Kh, const ushort_t* __restrict__ Vh,
    const bf16x8& qf0, const bf16x8& qf1,
    float (&scur)[4][4], float (&snxt)[4][4],
    f32x4 (&macc)[4], float (&lrun)[4],
    ushort_t (* __restrict__ Pw)[72], int l15, int lhi, int lane)
{
    // prefetch next tile's mask (16 scalar loads, 4 segments each)
#pragma unroll
    for (int r = 0; r < 4; ++r)
#pragma unroll
        for (int kb = 0; kb < 4; ++kb)
            snxt[r][kb] = Sgw[(size_t)r * NPTS + ktn * 64 + kb * 16];

    // QK^T: sacc[kb][r] = score[q=lhi*4+r][key=kb*16+l15]
    f32x4 sacc[4];
#pragma unroll
    for (int kb = 0; kb < 4; ++kb) {
        const ushort_t* kp = Kh + (size_t)(kt * 4 + kb) * 1024 + lane * 8;
        bf16x8 kf0 = *(const bf16x8*)kp;
        bf16x8 kf1 = *(const bf16x8*)(kp + 512);
        f32x4 z = (f32x4){0.f, 0.f, 0.f, 0.f};
        z = __builtin_amdgcn_mfma_f32_16x16x32_bf16(qf0, kf0, z, 0, 0, 0);
        z = __builtin_amdgcn_mfma_f32_16x16x32_bf16(qf1, kf1, z, 0, 0, 0);
        sacc[kb] = z;
    }

    // issue V loads; exp + LDS round-trip covers their latency
    bf16x8 vf[8];
    const ushort_t* vb = Vh + (size_t)kt * 4096 + lane * 8;
#pragma unroll
    for (int mm = 0; mm < 2; ++mm)
#pragma unroll
        for (int db = 0; db < 4; ++db)
            vf[mm * 4 + db] = *(const bf16x8*)(vb + db * 1024 + mm * 512);

    // p = exp(score * mask); per-lane l partials; P -> LDS [q][k]
#pragma unroll
    for (int kb = 0; kb < 4; ++kb) {
#pragma unroll
        for (int r = 0; r < 4; ++r) {
            float p = __expf(sacc[kb][r] * scur[r][kb]);
            lrun[r] += p;
            Pw[lhi * 4 + r][kb * 16 + l15] = f2bf(p);
        }
    }
    // same-wave RAW through LDS; compiler inserts lgkmcnt wait

    // PV: mfma(A=V row=d, B=P col=q)
#pragma unroll
    for (int mm = 0; mm < 2; ++mm) {
        bf16x8 pf = *(const bf16x8*)&Pw[l15][mm * 32 + lhi * 8];
#pragma unroll
        for (int db = 0; db < 4; ++db)
            macc[db] = __builtin_amdgcn_mfma_f32_16x16x32_bf16(vf[mm * 4 + db], pf, macc[db], 0, 0, 0);
    }
}

// ---------------------------------------------------------------------------
// MFMA flash attention: per-head blocks, key-split 8, fragment-major K/V/Q,
// register-direct row-major S (no prep, no staging), no-max softmax.
// ---------------------------------------------------------------------------
__global__ __launch_bounds__(256, 4) void attn_mfma(
    const ushort_t* __restrict__ Qf, const ushort_t* __restrict__ Kf,
    const ushort_t* __restrict__ Vf, const float* __restrict__ S,
    ushort_t* __restrict__ pacc, float* __restrict__ pl)
{
    __shared__ __align__(16) ushort_t P_lds[4][16][72];   // 9216 B

    const int tid  = threadIdx.x;
    const int w    = tid >> 6;
    const int lane = tid & 63;
    const int l15  = lane & 15;
    const int lhi  = lane >> 4;
    const int h    = blockIdx.y;
    const int ks   = blockIdx.z;
    const int q0   = blockIdx.x * 64 + w * 16;
    const int ktb  = ks * (KCHUNK / 64);

    const ushort_t* Kh = Kf + (size_t)h * HSTRIDE;
    const ushort_t* Vh = Vf + (size_t)h * HSTRIDE;
    // lane's mask base: row q0+lhi*4 (+r rows), col l15 (+kt*64+kb*16)
    const float* Sgw = S + (size_t)(q0 + lhi * 4) * NPTS + l15;
    ushort_t (* __restrict__ Pw)[72] = P_lds[w];

    bf16x8 qf0, qf1;
    {
        const ushort_t* qp = Qf + (size_t)h * HSTRIDE + (size_t)(q0 >> 4) * 1024 + lane * 8;
        qf0 = *(const bf16x8*)qp;
        qf1 = *(const bf16x8*)(qp + 512);
    }

    f32x4 macc[4];
#pragma unroll
    for (int db = 0; db < 4; ++db) macc[db] = (f32x4){0.f, 0.f, 0.f, 0.f};
    float lrun[4];
#pragma unroll
    for (int r = 0; r < 4; ++r) lrun[r] = 0.0f;

    // prologue: mask tile ktb into sA
    float sA[4][4], sB[4][4];
#pragma unroll
    for (int r = 0; r < 4; ++r)
#pragma unroll
        for (int kb = 0; kb < 4; ++kb)
            sA[r][kb] = Sgw[(size_t)r * NPTS + ktb * 64 + kb * 16];

    // 8 tiles -> 4 pair-iterations (static A/B buffers; wrap harmless)
    for (int kt = ktb; kt < ktb + 8; kt += 2) {
        const int kt2 = (kt + 2 < ktb + 8) ? kt + 2 : ktb;
        attn_tile(kt,     kt + 1, Sgw, Kh, Vh, qf0, qf1, sA, sB, macc, lrun, Pw, l15, lhi, lane);
        attn_tile(kt + 1, kt2,    Sgw, Kh, Vh, qf0, qf1, sB, sA, macc, lrun, Pw, l15, lhi, lane);
    }

    // deferred l reduction across the 16 key-lanes (once per block)
#pragma unroll
    for (int r = 0; r < 4; ++r) {
        lrun[r] += __shfl_xor(lrun[r], 1);
        lrun[r] += __shfl_xor(lrun[r], 2);
        lrun[r] += __shfl_xor(lrun[r], 4);
        lrun[r] += __shfl_xor(lrun[r], 8);
    }

    // store unnormalized partials (C col=q=l15, row=d) + l sums
    const size_t pb = ((size_t)ks * NHEAD + h) * NPTS;
    ushort_t* prow = pacc + (pb + q0 + l15) * DHEAD;
#pragma unroll
    for (int db = 0; db < 4; ++db) {
        *(unsigned*)&prow[db * 16 + lhi * 4]     = pack2bf(macc[db][0], macc[db][1]);
        *(unsigned*)&prow[db * 16 + lhi * 4 + 2] = pack2bf(macc[db][2], macc[db][3]);
    }
    if (l15 == 0) {
#pragma unroll
        for (int r = 0; r < 4; ++r)
            pl[pb + q0 + lhi * 4 + r] = lrun[r];
    }
}

// ---------------------------------------------------------------------------
// Merge KSPLIT partials (common scale) -> msgT [N][256] bf16.
// ---------------------------------------------------------------------------
__global__ __launch_bounds__(256) void attn_merge(
    const ushort_t* __restrict__ pacc, const float* __restrict__ pl,
    ushort_t* __restrict__ msgT)
{
    const int h = blockIdx.y;
    const int q = blockIdx.x * 64 + (threadIdx.x >> 2);
    const int d0 = (threadIdx.x & 3) * 16;

    float ls = 0.0f;
#pragma unroll
    for (int ks = 0; ks < KSPLIT; ++ks)
        ls += pl[((size_t)ks * NHEAD + h) * NPTS + q];
    float inv = 1.0f / ls;

    float out[16];
#pragma unroll
    for (int j = 0; j < 16; ++j) out[j] = 0.0f;
#pragma unroll
    for (int ks = 0; ks < KSPLIT; ++ks) {
        const ushort_t* ap = pacc + (((size_t)ks * NHEAD + h) * NPTS + q) * DHEAD + d0;
        bf16x8 v0 = *(const bf16x8*)ap;
        bf16x8 v1 = *(const bf16x8*)(ap + 8);
#pragma unroll
        for (int j = 0; j < 8; ++j) {
            out[j]     += bf2f((ushort_t)v0[j]);
            out[8 + j] += bf2f((ushort_t)v1[j]);
        }
    }
    bf16x8 o0, o1;
#pragma unroll
    for (int j = 0; j < 8; ++j) {
        o0[j] = (short)f2bf(out[j] * inv);
        o1[j] = (short)f2bf(out[8 + j] * inv);
    }
    ushort_t* op = msgT + (size_t)q * D_CH + h * DHEAD + d0;
    *(bf16x8*)op = o0;
    *(bf16x8*)(op + 8) = o1;
}

// ---------------------------------------------------------------------------
extern "C" void kernel_launch(void* const* d_in, const int* in_sizes, int n_in,
                              void* d_out, int out_size, void* d_ws, size_t ws_size,
                              hipStream_t stream) {
    const float* x  = (const float*)d_in[0];
    const float* S  = (const float*)d_in[1];
    const float* Wq = (const float*)d_in[2];
    const float* bq = (const float*)d_in[3];
    const float* Wk = (const float*)d_in[4];
    const float* bk = (const float*)d_in[5];
    const float* Wv = (const float*)d_in[6];
    const float* bv = (const float*)d_in[7];
    const float* W1 = (const float*)d_in[8];
    const float* b1 = (const float*)d_in[9];
    const float* g1 = (const float*)d_in[10];
    const float* be1= (const float*)d_in[11];
    const float* W2 = (const float*)d_in[12];
    const float* b2 = (const float*)d_in[13];
    const float* g2 = (const float*)d_in[14];
    const float* be2= (const float*)d_in[15];
    const float* W3 = (const float*)d_in[16];
    const float* b3 = (const float*)d_in[17];

    char* ws = (char*)d_ws;
    const size_t MB = 1024 * 1024;
    ushort_t* xT   = (ushort_t*)(ws);                        // 2 MB
    ushort_t* Qf   = (ushort_t*)(ws + 2 * MB);               // 2 MB
    ushort_t* Kf   = (ushort_t*)(ws + 4 * MB);               // 2 MB
    ushort_t* Vf   = (ushort_t*)(ws + 6 * MB);               // 2 MB
    ushort_t* pacc = (ushort_t*)(ws + 8 * MB);               // 16 MB
    float*    pl   = (float*)   (ws + 24 * MB);              // 512 KB
    ushort_t* msgT = (ushort_t*)(ws + 25 * MB);              // 2 MB
    ushort_t* h1T  = (ushort_t*)(ws + 27 * MB);              // 1 MB
    ushort_t* h2T  = (ushort_t*)(ws + 28 * MB);              // 1 MB

    transpose_cast<<<dim3(64, 4), 256, 0, stream>>>(x, xT);
    gemm_qkv<<<dim3(64, 4, 3), 256, 0, stream>>>(Wq, bq, Wk, bk, Wv, bv, xT, Qf, Kf, Vf);

    attn_mfma<<<dim3(64, NHEAD, KSPLIT), 256, 0, stream>>>(Qf, Kf, Vf, S, pacc, pl);
    attn_merge<<<dim3(64, NHEAD), 256, 0, stream>>>(pacc, pl, msgT);

    gemm_mfma32<<<dim3(64, 4), 256, 0, stream>>>(W1, msgT, h1T, 128, NPTS, 256, b1, g1, be1, 1, nullptr, 3);
    gemm_mfma32<<<dim3(64, 4), 256, 0, stream>>>(W2, h1T, h2T, 128, NPTS, 128, b2, g2, be2, 1, nullptr, 3);
    gemm_mfma32<<<dim3(64, 8), 256, 0, stream>>>(W3, h2T, d_out, 256, NPTS, 128, b3, nullptr, nullptr, 0, x, 0);
}

// Round 14
// 106.332 us; speedup vs baseline: 1.1831x; 1.0223x over previous
//
#include <hip/hip_runtime.h>
#include <hip/hip_bf16.h>
#include <math.h>

#define D_CH   256
#define NHEAD  4
#define DHEAD  64
#define NPTS   4096
#define KSPLIT 8
#define KCHUNK (NPTS / KSPLIT)          // 512 keys = 8 tiles of 64
#define BN_RSQ 0.99999500003749963f     // 1/sqrt(1 + 1e-5)
#define HSTRIDE 262144                  // 4096*64 ushorts per head

typedef __attribute__((ext_vector_type(4))) float f32x4;
typedef __attribute__((ext_vector_type(8))) short bf16x8;
typedef unsigned short ushort_t;

__device__ __forceinline__ ushort_t f2bf(float x) {
    unsigned int b = __float_as_uint(x);
    return (ushort_t)((b + 0x7FFF + ((b >> 16) & 1)) >> 16);  // RNE
}
__device__ __forceinline__ float bf2f(ushort_t u) {
    return __uint_as_float(((unsigned int)u) << 16);
}
__device__ __forceinline__ unsigned pack2bf(float lo, float hi) {
    return (unsigned)f2bf(lo) | ((unsigned)f2bf(hi) << 16);
}

// ---------------------------------------------------------------------------
// prep: transpose-cast x [256][4096] f32 -> xT [4096][256] bf16
// ---------------------------------------------------------------------------
__global__ __launch_bounds__(256) void transpose_cast(
    const float* __restrict__ x, ushort_t* __restrict__ xT)
{
    __shared__ float xs[64][65];
    const int tid = threadIdx.x;
    const int n0 = blockIdx.x * 64, k0 = blockIdx.y * 64;
#pragma unroll
    for (int p = 0; p < 16; ++p) {
        int kk = p * 4 + (tid >> 6), nn = tid & 63;
        xs[kk][nn] = x[(size_t)(k0 + kk) * NPTS + n0 + nn];
    }
    __syncthreads();
#pragma unroll
    for (int p = 0; p < 16; ++p) {
        int nn = p * 4 + (tid >> 6), kk = tid & 63;
        xT[(size_t)(n0 + nn) * D_CH + k0 + kk] = f2bf(xs[kk][nn]);
    }
}

// ---------------------------------------------------------------------------
// Shared MFMA GEMM tile body: acc[2][2] = sum_k A[m][k]*Bt[n][k]
// ---------------------------------------------------------------------------
__device__ __forceinline__ void gemm_tile_body(
    const float* __restrict__ A, const ushort_t* __restrict__ Bt,
    int K, int m0, int n0, int l15, int lhi, f32x4 acc[2][2])
{
#pragma unroll
    for (int i = 0; i < 2; ++i)
#pragma unroll
        for (int j = 0; j < 2; ++j) acc[i][j] = (f32x4){0.f, 0.f, 0.f, 0.f};

    for (int k0 = 0; k0 < K; k0 += 32) {
        bf16x8 af[2], bfr[2];
#pragma unroll
        for (int mf = 0; mf < 2; ++mf) {
            const float* ap = A + (size_t)(m0 + mf * 16 + l15) * K + k0 + lhi * 8;
            float4 a0 = *(const float4*)ap;
            float4 a1 = *(const float4*)(ap + 4);
            bf16x8 t;
            t[0] = (short)f2bf(a0.x); t[1] = (short)f2bf(a0.y);
            t[2] = (short)f2bf(a0.z); t[3] = (short)f2bf(a0.w);
            t[4] = (short)f2bf(a1.x); t[5] = (short)f2bf(a1.y);
            t[6] = (short)f2bf(a1.z); t[7] = (short)f2bf(a1.w);
            af[mf] = t;
        }
#pragma unroll
        for (int nf = 0; nf < 2; ++nf)
            bfr[nf] = *(const bf16x8*)&Bt[(size_t)(n0 + nf * 16 + l15) * K + k0 + lhi * 8];
#pragma unroll
        for (int mf = 0; mf < 2; ++mf)
#pragma unroll
            for (int nf = 0; nf < 2; ++nf)
                acc[mf][nf] = __builtin_amdgcn_mfma_f32_16x16x32_bf16(af[mf], bfr[nf], acc[mf][nf], 0, 0, 0);
    }
}

// ---------------------------------------------------------------------------
// Fused QKV projection -> fragment-major layouts (0.125 folded into Q).
// ---------------------------------------------------------------------------
__global__ __launch_bounds__(256) void gemm_qkv(
    const float* __restrict__ Wq, const float* __restrict__ bq,
    const float* __restrict__ Wk, const float* __restrict__ bk,
    const float* __restrict__ Wv, const float* __restrict__ bv,
    const ushort_t* __restrict__ xT,
    ushort_t* __restrict__ Qf, ushort_t* __restrict__ Kf, ushort_t* __restrict__ Vf)
{
    const int tid = threadIdx.x;
    const int w = tid >> 6, lane = tid & 63, l15 = lane & 15, lhi = lane >> 4;
    const int wm = w >> 1, wn = w & 1;
    const int m0 = blockIdx.y * 64 + wm * 32;
    const int n0 = blockIdx.x * 64 + wn * 32;
    const int z = blockIdx.z;

    const float* A    = (z == 0) ? Wq : (z == 1) ? Wk : Wv;
    const float* bias = (z == 0) ? bq : (z == 1) ? bk : bv;
    ushort_t* dst     = (z == 0) ? Qf : (z == 1) ? Kf : Vf;
    const float scl   = (z == 0) ? 0.125f : 1.0f;

    f32x4 acc[2][2];
    gemm_tile_body(A, xT, D_CH, m0, n0, l15, lhi, acc);

#pragma unroll
    for (int mf = 0; mf < 2; ++mf) {
#pragma unroll
        for (int r = 0; r < 4; ++r) {
            int m = m0 + mf * 16 + lhi * 4 + r;
            int head = m >> 6, dch = m & 63;
            float bi = bias[m];
#pragma unroll
            for (int nf = 0; nf < 2; ++nf) {
                int n = n0 + nf * 16 + l15;
                float v = (acc[mf][nf][r] + bi) * scl;
                size_t idx;
                if (z < 2)
                    idx = (size_t)head * HSTRIDE + (size_t)(n >> 4) * 1024 + (dch >> 5) * 512
                        + (((dch >> 3) & 3) * 16 + (n & 15)) * 8 + (dch & 7);
                else
                    idx = (size_t)head * HSTRIDE + (size_t)(n >> 6) * 4096 + (dch >> 4) * 1024
                        + ((n >> 5) & 1) * 512 + (((n >> 3) & 3) * 16 + (dch & 15)) * 8 + (n & 7);
                dst[idx] = f2bf(v);
            }
        }
    }
}

// ---------------------------------------------------------------------------
// Small-tile MFMA GEMM for the MLP chain: block tile 32(M) x 64(N).
// out_mode: 0 = f32 C[m][n] (+resid);  3 = bf16 transposed Cu[n*M + m]
// ---------------------------------------------------------------------------
__global__ __launch_bounds__(256) void gemm_mfma32(
    const float* __restrict__ A, const ushort_t* __restrict__ Bt,
    void* __restrict__ Cout, int M, int N, int K,
    const float* __restrict__ bias, const float* __restrict__ gamma,
    const float* __restrict__ beta, int relu, const float* __restrict__ resid,
    int out_mode)
{
    const int tid = threadIdx.x;
    const int w = tid >> 6, lane = tid & 63, l15 = lane & 15, lhi = lane >> 4;
    const int wm = w >> 1, wn = w & 1;
    const int m0 = blockIdx.y * 32 + wm * 16;
    const int n0 = blockIdx.x * 64 + wn * 32;

    f32x4 acc[2];
#pragma unroll
    for (int j = 0; j < 2; ++j) acc[j] = (f32x4){0.f, 0.f, 0.f, 0.f};

    for (int k0 = 0; k0 < K; k0 += 32) {
        const float* ap = A + (size_t)(m0 + l15) * K + k0 + lhi * 8;
        float4 a0 = *(const float4*)ap;
        float4 a1 = *(const float4*)(ap + 4);
        bf16x8 af;
        af[0] = (short)f2bf(a0.x); af[1] = (short)f2bf(a0.y);
        af[2] = (short)f2bf(a0.z); af[3] = (short)f2bf(a0.w);
        af[4] = (short)f2bf(a1.x); af[5] = (short)f2bf(a1.y);
        af[6] = (short)f2bf(a1.z); af[7] = (short)f2bf(a1.w);
#pragma unroll
        for (int nf = 0; nf < 2; ++nf) {
            bf16x8 bfr = *(const bf16x8*)&Bt[(size_t)(n0 + nf * 16 + l15) * K + k0 + lhi * 8];
            acc[nf] = __builtin_amdgcn_mfma_f32_16x16x32_bf16(af, bfr, acc[nf], 0, 0, 0);
        }
    }

    float* Cf = (float*)Cout;
    ushort_t* Cu = (ushort_t*)Cout;
#pragma unroll
    for (int r = 0; r < 4; ++r) {
        int m = m0 + lhi * 4 + r;
        float bi = bias[m];
        float sc = 1.0f, sh = 0.0f;
        if (gamma) { sc = gamma[m] * BN_RSQ; sh = beta[m]; }
#pragma unroll
        for (int nf = 0; nf < 2; ++nf) {
            int n = n0 + nf * 16 + l15;
            float v = acc[nf][r] + bi;
            if (gamma) v = v * sc + sh;
            if (relu)  v = fmaxf(v, 0.0f);
            if (resid) v += resid[(size_t)m * N + n];
            if (out_mode == 0) Cf[(size_t)m * N + n] = v;
            else               Cu[(size_t)n * M + m] = f2bf(v);
        }
    }
}

// ---------------------------------------------------------------------------
// One 64-key tile, TWO q-fragments per warp (32 queries), no-max softmax,
// single-buffered bf16 per-warp mask staging (r11 mechanism, 32 rows):
//  - K and V fragment loads are SHARED by both q-fragments (per-q cost /2)
//  - QK/exp/PV for the two fragments are independent chains (2x ILP)
//  - next tile's S loads issued at tile start (coalesced 4x256B rows x 8);
//    written to the same warp-private buffer right after this tile's mask
//    reads (in-order wave LDS => race-free, and the S regs die mid-tile)
// ---------------------------------------------------------------------------
__device__ __forceinline__ void attn_tile(
    int kt, int ktn, const float* __restrict__ Sg,
    const ushort_t* __restrict__ Kh, const ushort_t* __restrict__ Vh,
    const bf16x8 (&qf)[2][2],
    ushort_t (* __restrict__ Sw)[72],
    f32x4 (&macc)[2][4], float (&lrun)[2],
    ushort_t (* __restrict__ Pw)[72], int l15, int lhi, int lane)
{
    // issue next tile's mask loads (8 instr, 4x256B segments each)
    f32x4 sr[8];
#pragma unroll
    for (int p = 0; p < 8; ++p)
        sr[p] = *(const f32x4*)&Sg[(size_t)p * 4 * NPTS + (size_t)ktn * 64];

    // QK^T swapped for both q-frags: sacc[f][kb][r] = score[key][q=f*16+l15]
    f32x4 sacc0[4], sacc1[4];
#pragma unroll
    for (int kb = 0; kb < 4; ++kb) {
        const ushort_t* kp = Kh + (size_t)(kt * 4 + kb) * 1024 + lane * 8;
        bf16x8 kf0 = *(const bf16x8*)kp;
        bf16x8 kf1 = *(const bf16x8*)(kp + 512);
        f32x4 z0 = (f32x4){0.f, 0.f, 0.f, 0.f};
        z0 = __builtin_amdgcn_mfma_f32_16x16x32_bf16(kf0, qf[0][0], z0, 0, 0, 0);
        z0 = __builtin_amdgcn_mfma_f32_16x16x32_bf16(kf1, qf[0][1], z0, 0, 0, 0);
        sacc0[kb] = z0;
        f32x4 z1 = (f32x4){0.f, 0.f, 0.f, 0.f};
        z1 = __builtin_amdgcn_mfma_f32_16x16x32_bf16(kf0, qf[1][0], z1, 0, 0, 0);
        z1 = __builtin_amdgcn_mfma_f32_16x16x32_bf16(kf1, qf[1][1], z1, 0, 0, 0);
        sacc1[kb] = z1;
    }

    // issue V loads (shared by both fragments)
    bf16x8 vf[8];
    const ushort_t* vb = Vh + (size_t)kt * 4096 + lane * 8;
#pragma unroll
    for (int mm = 0; mm < 2; ++mm)
#pragma unroll
        for (int db = 0; db < 4; ++db)
            vf[mm * 4 + db] = *(const bf16x8*)(vb + db * 1024 + mm * 512);

    // p = exp(score * mask), both fragments; pack -> P_lds
    float ts0 = 0.0f, ts1 = 0.0f;
#pragma unroll
    for (int kb = 0; kb < 4; ++kb) {
        unsigned a0 = *(const unsigned*)&Sw[l15][kb * 16 + lhi * 4];
        unsigned a1 = *(const unsigned*)&Sw[l15][kb * 16 + lhi * 4 + 2];
        unsigned b0 = *(const unsigned*)&Sw[16 + l15][kb * 16 + lhi * 4];
        unsigned b1 = *(const unsigned*)&Sw[16 + l15][kb * 16 + lhi * 4 + 2];
        float p00 = __expf(sacc0[kb][0] * bf2f((ushort_t)(a0 & 0xFFFF)));
        float p01 = __expf(sacc0[kb][1] * bf2f((ushort_t)(a0 >> 16)));
        float p02 = __expf(sacc0[kb][2] * bf2f((ushort_t)(a1 & 0xFFFF)));
        float p03 = __expf(sacc0[kb][3] * bf2f((ushort_t)(a1 >> 16)));
        float p10 = __expf(sacc1[kb][0] * bf2f((ushort_t)(b0 & 0xFFFF)));
        float p11 = __expf(sacc1[kb][1] * bf2f((ushort_t)(b0 >> 16)));
        float p12 = __expf(sacc1[kb][2] * bf2f((ushort_t)(b1 & 0xFFFF)));
        float p13 = __expf(sacc1[kb][3] * bf2f((ushort_t)(b1 >> 16)));
        ts0 += (p00 + p01) + (p02 + p03);
        ts1 += (p10 + p11) + (p12 + p13);
        *(unsigned*)&Pw[l15][kb * 16 + lhi * 4]          = pack2bf(p00, p01);
        *(unsigned*)&Pw[l15][kb * 16 + lhi * 4 + 2]      = pack2bf(p02, p03);
        *(unsigned*)&Pw[16 + l15][kb * 16 + lhi * 4]     = pack2bf(p10, p11);
        *(unsigned*)&Pw[16 + l15][kb * 16 + lhi * 4 + 2] = pack2bf(p12, p13);
    }
    lrun[0] += ts0;
    lrun[1] += ts1;

    // store next tile's mask now (all Sw reads for this tile are done;
    // sr registers die here, lowering peak pressure through PV)
#pragma unroll
    for (int p = 0; p < 8; ++p) {
        *(unsigned*)&Sw[p * 4 + lhi][l15 * 4]     = pack2bf(sr[p][0], sr[p][1]);
        *(unsigned*)&Sw[p * 4 + lhi][l15 * 4 + 2] = pack2bf(sr[p][2], sr[p][3]);
    }

    // PV: mfma(A=V row=d, B=P col=q), both fragments share vf
#pragma unroll
    for (int mm = 0; mm < 2; ++mm) {
        bf16x8 pf0 = *(const bf16x8*)&Pw[l15][mm * 32 + lhi * 8];
        bf16x8 pf1 = *(const bf16x8*)&Pw[16 + l15][mm * 32 + lhi * 8];
#pragma unroll
        for (int db = 0; db < 4; ++db) {
            macc[0][db] = __builtin_amdgcn_mfma_f32_16x16x32_bf16(vf[mm * 4 + db], pf0, macc[0][db], 0, 0, 0);
            macc[1][db] = __builtin_amdgcn_mfma_f32_16x16x32_bf16(vf[mm * 4 + db], pf1, macc[1][db], 0, 0, 0);
        }
    }
}

// ---------------------------------------------------------------------------
// MFMA flash attention: 32 queries/warp (two 16q fragments), per-head
// blocks, key-split 8, fragment-major K/V/Q, in-kernel coalesced S staging.
// Grid (32, NHEAD, KSPLIT); block 256 (4 warps x 32q = 128 q/block).
// ---------------------------------------------------------------------------
__global__ __launch_bounds__(256, 3) void attn_mfma(
    const ushort_t* __restrict__ Qf, const ushort_t* __restrict__ Kf,
    const ushort_t* __restrict__ Vf, const float* __restrict__ S,
    ushort_t* __restrict__ pacc, float* __restrict__ pl)
{
    __shared__ __align__(16) ushort_t P_lds[4][32][72];   // 18432 B
    __shared__ __align__(16) ushort_t S_lds[4][32][72];   // 18432 B

    const int tid  = threadIdx.x;
    const int w    = tid >> 6;
    const int lane = tid & 63;
    const int l15  = lane & 15;
    const int lhi  = lane >> 4;
    const int h    = blockIdx.y;
    const int ks   = blockIdx.z;
    const int q0   = blockIdx.x * 128 + w * 32;
    const int ktb  = ks * (KCHUNK / 64);

    const ushort_t* Kh = Kf + (size_t)h * HSTRIDE;
    const ushort_t* Vh = Vf + (size_t)h * HSTRIDE;
    // lane's S pointer: rows q0+lhi+4p (p=0..7), cols l15*4..+3 (+kt*64)
    const float* Sg = S + (size_t)(q0 + lhi) * NPTS + l15 * 4;
    ushort_t (* __restrict__ Pw)[72] = P_lds[w];
    ushort_t (* __restrict__ Sw)[72] = S_lds[w];

    // Q fragments for both 16q groups
    bf16x8 qf[2][2];
#pragma unroll
    for (int f = 0; f < 2; ++f) {
        const ushort_t* qp = Qf + (size_t)h * HSTRIDE
                           + (size_t)((q0 + f * 16) >> 4) * 1024 + lane * 8;
        qf[f][0] = *(const bf16x8*)qp;
        qf[f][1] = *(const bf16x8*)(qp + 512);
    }

    f32x4 macc[2][4];
#pragma unroll
    for (int f = 0; f < 2; ++f)
#pragma unroll
        for (int db = 0; db < 4; ++db) macc[f][db] = (f32x4){0.f, 0.f, 0.f, 0.f};
    float lrun[2] = {0.0f, 0.0f};

    // prologue: stage mask tile ktb
    {
#pragma unroll
        for (int p = 0; p < 8; ++p) {
            f32x4 t = *(const f32x4*)&Sg[(size_t)p * 4 * NPTS + (size_t)ktb * 64];
            *(unsigned*)&Sw[p * 4 + lhi][l15 * 4]     = pack2bf(t[0], t[1]);
            *(unsigned*)&Sw[p * 4 + lhi][l15 * 4 + 2] = pack2bf(t[2], t[3]);
        }
    }

    // 8 tiles; prefetch distance 1 (wrap on last is harmless)
    for (int kt = ktb; kt < ktb + 8; ++kt) {
        const int ktn = (kt + 1 < ktb + 8) ? kt + 1 : ktb;
        attn_tile(kt, ktn, Sg, Kh, Vh, qf, Sw, macc, lrun, Pw, l15, lhi, lane);
    }

    // deferred cross-group l reduction (once per block)
#pragma unroll
    for (int f = 0; f < 2; ++f) {
        lrun[f] += __shfl_xor(lrun[f], 16);
        lrun[f] += __shfl_xor(lrun[f], 32);
    }

    // store unnormalized partials for both fragments
    const size_t pb = ((size_t)ks * NHEAD + h) * NPTS;
#pragma unroll
    for (int f = 0; f < 2; ++f) {
        ushort_t* prow = pacc + (pb + q0 + f * 16 + l15) * DHEAD;
#pragma unroll
        for (int db = 0; db < 4; ++db) {
            *(unsigned*)&prow[db * 16 + lhi * 4]     = pack2bf(macc[f][db][0], macc[f][db][1]);
            *(unsigned*)&prow[db * 16 + lhi * 4 + 2] = pack2bf(macc[f][db][2], macc[f][db][3]);
        }
    }
    if (lane < 16) {
        pl[pb + q0 + lane]      = lrun[0];
        pl[pb + q0 + 16 + lane] = lrun[1];
    }
}

// ---------------------------------------------------------------------------
// Merge KSPLIT partials (common scale) -> msgT [N][256] bf16.
// ---------------------------------------------------------------------------
__global__ __launch_bounds__(256) void attn_merge(
    const ushort_t* __restrict__ pacc, const float* __restrict__ pl,
    ushort_t* __restrict__ msgT)
{
    const int h = blockIdx.y;
    const int q = blockIdx.x * 64 + (threadIdx.x >> 2);
    const int d0 = (threadIdx.x & 3) * 16;

    float ls = 0.0f;
#pragma unroll
    for (int ks = 0; ks < KSPLIT; ++ks)
        ls += pl[((size_t)ks * NHEAD + h) * NPTS + q];
    float inv = 1.0f / ls;

    float out[16];
#pragma unroll
    for (int j = 0; j < 16; ++j) out[j] = 0.0f;
#pragma unroll
    for (int ks = 0; ks < KSPLIT; ++ks) {
        const ushort_t* ap = pacc + (((size_t)ks * NHEAD + h) * NPTS + q) * DHEAD + d0;
        bf16x8 v0 = *(const bf16x8*)ap;
        bf16x8 v1 = *(const bf16x8*)(ap + 8);
#pragma unroll
        for (int j = 0; j < 8; ++j) {
            out[j]     += bf2f((ushort_t)v0[j]);
            out[8 + j] += bf2f((ushort_t)v1[j]);
        }
    }
    bf16x8 o0, o1;
#pragma unroll
    for (int j = 0; j < 8; ++j) {
        o0[j] = (short)f2bf(out[j] * inv);
        o1[j] = (short)f2bf(out[8 + j] * inv);
    }
    ushort_t* op = msgT + (size_t)q * D_CH + h * DHEAD + d0;
    *(bf16x8*)op = o0;
    *(bf16x8*)(op + 8) = o1;
}

// ---------------------------------------------------------------------------
extern "C" void kernel_launch(void* const* d_in, const int* in_sizes, int n_in,
                              void* d_out, int out_size, void* d_ws, size_t ws_size,
                              hipStream_t stream) {
    const float* x  = (const float*)d_in[0];
    const float* S  = (const float*)d_in[1];
    const float* Wq = (const float*)d_in[2];
    const float* bq = (const float*)d_in[3];
    const float* Wk = (const float*)d_in[4];
    const float* bk = (const float*)d_in[5];
    const float* Wv = (const float*)d_in[6];
    const float* bv = (const float*)d_in[7];
    const float* W1 = (const float*)d_in[8];
    const float* b1 = (const float*)d_in[9];
    const float* g1 = (const float*)d_in[10];
    const float* be1= (const float*)d_in[11];
    const float* W2 = (const float*)d_in[12];
    const float* b2 = (const float*)d_in[13];
    const float* g2 = (const float*)d_in[14];
    const float* be2= (const float*)d_in[15];
    const float* W3 = (const float*)d_in[16];
    const float* b3 = (const float*)d_in[17];

    char* ws = (char*)d_ws;
    const size_t MB = 1024 * 1024;
    ushort_t* xT   = (ushort_t*)(ws);                        // 2 MB
    ushort_t* Qf   = (ushort_t*)(ws + 2 * MB);               // 2 MB
    ushort_t* Kf   = (ushort_t*)(ws + 4 * MB);               // 2 MB
    ushort_t* Vf   = (ushort_t*)(ws + 6 * MB);               // 2 MB
    ushort_t* pacc = (ushort_t*)(ws + 8 * MB);               // 16 MB
    float*    pl   = (float*)   (ws + 24 * MB);              // 512 KB
    ushort_t* msgT = (ushort_t*)(ws + 25 * MB);              // 2 MB
    ushort_t* h1T  = (ushort_t*)(ws + 27 * MB);              // 1 MB
    ushort_t* h2T  = (ushort_t*)(ws + 28 * MB);              // 1 MB

    transpose_cast<<<dim3(64, 4), 256, 0, stream>>>(x, xT);
    gemm_qkv<<<dim3(64, 4, 3), 256, 0, stream>>>(Wq, bq, Wk, bk, Wv, bv, xT, Qf, Kf, Vf);

    attn_mfma<<<dim3(32, NHEAD, KSPLIT), 256, 0, stream>>>(Qf, Kf, Vf, S, pacc, pl);
    attn_merge<<<dim3(64, NHEAD), 256, 0, stream>>>(pacc, pl, msgT);

    gemm_mfma32<<<dim3(64, 4), 256, 0, stream>>>(W1, msgT, h1T, 128, NPTS, 256, b1, g1, be1, 1, nullptr, 3);
    gemm_mfma32<<<dim3(64, 4), 256, 0, stream>>>(W2, h1T, h2T, 128, NPTS, 128, b2, g2, be2, 1, nullptr, 3);
    gemm_mfma32<<<dim3(64, 8), 256, 0, stream>>>(W3, h2T, d_out, 256, NPTS, 128, b3, nullptr, nullptr, 0, x, 0);
}

// Round 15
// 101.748 us; speedup vs baseline: 1.2365x; 1.0451x over previous
//
#include <hip/hip_runtime.h>
#include <hip/hip_bf16.h>
#include <math.h>

#define D_CH   256
#define NHEAD  4
#define DHEAD  64
#define NPTS   4096
#define KSPLIT 8
#define KCHUNK (NPTS / KSPLIT)          // 512 keys = 8 tiles of 64
#define BN_RSQ 0.99999500003749963f     // 1/sqrt(1 + 1e-5)
#define HSTRIDE 262144                  // 4096*64 ushorts per head

typedef __attribute__((ext_vector_type(4))) float f32x4;
typedef __attribute__((ext_vector_type(8))) short bf16x8;
typedef unsigned short ushort_t;

__device__ __forceinline__ ushort_t f2bf(float x) {
    unsigned int b = __float_as_uint(x);
    return (ushort_t)((b + 0x7FFF + ((b >> 16) & 1)) >> 16);  // RNE (scalar fallback)
}
__device__ __forceinline__ float bf2f(ushort_t u) {
    return __uint_as_float(((unsigned int)u) << 16);
}
// HW packed f32x2 -> bf16x2 (RNE), single VALU op (T12 primitive, m240)
__device__ __forceinline__ unsigned cvt_pk(float lo, float hi) {
    unsigned r;
    asm("v_cvt_pk_bf16_f32 %0, %1, %2" : "=v"(r) : "v"(lo), "v"(hi));
    return r;
}

// ---------------------------------------------------------------------------
// prep: transpose-cast x [256][4096] f32 -> xT [4096][256] bf16
// ---------------------------------------------------------------------------
__global__ __launch_bounds__(256) void transpose_cast(
    const float* __restrict__ x, ushort_t* __restrict__ xT)
{
    __shared__ float xs[64][65];
    const int tid = threadIdx.x;
    const int n0 = blockIdx.x * 64, k0 = blockIdx.y * 64;
#pragma unroll
    for (int p = 0; p < 16; ++p) {
        int kk = p * 4 + (tid >> 6), nn = tid & 63;
        xs[kk][nn] = x[(size_t)(k0 + kk) * NPTS + n0 + nn];
    }
    __syncthreads();
#pragma unroll
    for (int p = 0; p < 16; ++p) {
        int nn = p * 4 + (tid >> 6), kk = tid & 63;
        xT[(size_t)(n0 + nn) * D_CH + k0 + kk] = f2bf(xs[kk][nn]);
    }
}

// ---------------------------------------------------------------------------
// Shared MFMA GEMM tile body: acc[2][2] = sum_k A[m][k]*Bt[n][k]
// A-cast uses HW cvt_pk (4 ops instead of ~48 per fragment).
// ---------------------------------------------------------------------------
__device__ __forceinline__ void gemm_tile_body(
    const float* __restrict__ A, const ushort_t* __restrict__ Bt,
    int K, int m0, int n0, int l15, int lhi, f32x4 acc[2][2])
{
#pragma unroll
    for (int i = 0; i < 2; ++i)
#pragma unroll
        for (int j = 0; j < 2; ++j) acc[i][j] = (f32x4){0.f, 0.f, 0.f, 0.f};

    for (int k0 = 0; k0 < K; k0 += 32) {
        bf16x8 af[2], bfr[2];
#pragma unroll
        for (int mf = 0; mf < 2; ++mf) {
            const float* ap = A + (size_t)(m0 + mf * 16 + l15) * K + k0 + lhi * 8;
            float4 a0 = *(const float4*)ap;
            float4 a1 = *(const float4*)(ap + 4);
            unsigned* tp = (unsigned*)&af[mf];
            tp[0] = cvt_pk(a0.x, a0.y);
            tp[1] = cvt_pk(a0.z, a0.w);
            tp[2] = cvt_pk(a1.x, a1.y);
            tp[3] = cvt_pk(a1.z, a1.w);
        }
#pragma unroll
        for (int nf = 0; nf < 2; ++nf)
            bfr[nf] = *(const bf16x8*)&Bt[(size_t)(n0 + nf * 16 + l15) * K + k0 + lhi * 8];
#pragma unroll
        for (int mf = 0; mf < 2; ++mf)
#pragma unroll
            for (int nf = 0; nf < 2; ++nf)
                acc[mf][nf] = __builtin_amdgcn_mfma_f32_16x16x32_bf16(af[mf], bfr[nf], acc[mf][nf], 0, 0, 0);
    }
}

// ---------------------------------------------------------------------------
// Fused QKV projection -> fragment-major layouts (0.125 folded into Q).
// ---------------------------------------------------------------------------
__global__ __launch_bounds__(256) void gemm_qkv(
    const float* __restrict__ Wq, const float* __restrict__ bq,
    const float* __restrict__ Wk, const float* __restrict__ bk,
    const float* __restrict__ Wv, const float* __restrict__ bv,
    const ushort_t* __restrict__ xT,
    ushort_t* __restrict__ Qf, ushort_t* __restrict__ Kf, ushort_t* __restrict__ Vf)
{
    const int tid = threadIdx.x;
    const int w = tid >> 6, lane = tid & 63, l15 = lane & 15, lhi = lane >> 4;
    const int wm = w >> 1, wn = w & 1;
    const int m0 = blockIdx.y * 64 + wm * 32;
    const int n0 = blockIdx.x * 64 + wn * 32;
    const int z = blockIdx.z;

    const float* A    = (z == 0) ? Wq : (z == 1) ? Wk : Wv;
    const float* bias = (z == 0) ? bq : (z == 1) ? bk : bv;
    ushort_t* dst     = (z == 0) ? Qf : (z == 1) ? Kf : Vf;
    const float scl   = (z == 0) ? 0.125f : 1.0f;

    f32x4 acc[2][2];
    gemm_tile_body(A, xT, D_CH, m0, n0, l15, lhi, acc);

#pragma unroll
    for (int mf = 0; mf < 2; ++mf) {
#pragma unroll
        for (int r = 0; r < 4; ++r) {
            int m = m0 + mf * 16 + lhi * 4 + r;
            int head = m >> 6, dch = m & 63;
            float bi = bias[m];
#pragma unroll
            for (int nf = 0; nf < 2; ++nf) {
                int n = n0 + nf * 16 + l15;
                float v = (acc[mf][nf][r] + bi) * scl;
                size_t idx;
                if (z < 2)
                    idx = (size_t)head * HSTRIDE + (size_t)(n >> 4) * 1024 + (dch >> 5) * 512
                        + (((dch >> 3) & 3) * 16 + (n & 15)) * 8 + (dch & 7);
                else
                    idx = (size_t)head * HSTRIDE + (size_t)(n >> 6) * 4096 + (dch >> 4) * 1024
                        + ((n >> 5) & 1) * 512 + (((n >> 3) & 3) * 16 + (dch & 15)) * 8 + (n & 7);
                dst[idx] = (ushort_t)(cvt_pk(v, v) & 0xFFFF);
            }
        }
    }
}

// ---------------------------------------------------------------------------
// Small-tile MFMA GEMM for the MLP chain: block tile 32(M) x 64(N).
// out_mode: 0 = f32 C[m][n] (+resid);  3 = bf16 transposed Cu[n*M + m]
// ---------------------------------------------------------------------------
__global__ __launch_bounds__(256) void gemm_mfma32(
    const float* __restrict__ A, const ushort_t* __restrict__ Bt,
    void* __restrict__ Cout, int M, int N, int K,
    const float* __restrict__ bias, const float* __restrict__ gamma,
    const float* __restrict__ beta, int relu, const float* __restrict__ resid,
    int out_mode)
{
    const int tid = threadIdx.x;
    const int w = tid >> 6, lane = tid & 63, l15 = lane & 15, lhi = lane >> 4;
    const int wm = w >> 1, wn = w & 1;
    const int m0 = blockIdx.y * 32 + wm * 16;
    const int n0 = blockIdx.x * 64 + wn * 32;

    f32x4 acc[2];
#pragma unroll
    for (int j = 0; j < 2; ++j) acc[j] = (f32x4){0.f, 0.f, 0.f, 0.f};

    for (int k0 = 0; k0 < K; k0 += 32) {
        const float* ap = A + (size_t)(m0 + l15) * K + k0 + lhi * 8;
        float4 a0 = *(const float4*)ap;
        float4 a1 = *(const float4*)(ap + 4);
        bf16x8 af;
        unsigned* tp = (unsigned*)&af;
        tp[0] = cvt_pk(a0.x, a0.y);
        tp[1] = cvt_pk(a0.z, a0.w);
        tp[2] = cvt_pk(a1.x, a1.y);
        tp[3] = cvt_pk(a1.z, a1.w);
#pragma unroll
        for (int nf = 0; nf < 2; ++nf) {
            bf16x8 bfr = *(const bf16x8*)&Bt[(size_t)(n0 + nf * 16 + l15) * K + k0 + lhi * 8];
            acc[nf] = __builtin_amdgcn_mfma_f32_16x16x32_bf16(af, bfr, acc[nf], 0, 0, 0);
        }
    }

    float* Cf = (float*)Cout;
    ushort_t* Cu = (ushort_t*)Cout;
#pragma unroll
    for (int r = 0; r < 4; ++r) {
        int m = m0 + lhi * 4 + r;
        float bi = bias[m];
        float sc = 1.0f, sh = 0.0f;
        if (gamma) { sc = gamma[m] * BN_RSQ; sh = beta[m]; }
#pragma unroll
        for (int nf = 0; nf < 2; ++nf) {
            int n = n0 + nf * 16 + l15;
            float v = acc[nf][r] + bi;
            if (gamma) v = v * sc + sh;
            if (relu)  v = fmaxf(v, 0.0f);
            if (resid) v += resid[(size_t)m * N + n];
            if (out_mode == 0) Cf[(size_t)m * N + n] = v;
            else               Cu[(size_t)n * M + m] = (ushort_t)(cvt_pk(v, v) & 0xFFFF);
        }
    }
}

// ---------------------------------------------------------------------------
// One 64-key tile, TWO q-fragments per warp (32 queries), no-max softmax,
// single-buffered bf16 per-warp mask staging. All packed bf16 conversions
// via HW v_cvt_pk_bf16_f32. MFMA clusters wrapped in s_setprio (T5).
// ---------------------------------------------------------------------------
__device__ __forceinline__ void attn_tile(
    int kt, int ktn, const float* __restrict__ Sg,
    const ushort_t* __restrict__ Kh, const ushort_t* __restrict__ Vh,
    const bf16x8 (&qf)[2][2],
    ushort_t (* __restrict__ Sw)[72],
    f32x4 (&macc)[2][4], float (&lrun)[2],
    ushort_t (* __restrict__ Pw)[72], int l15, int lhi, int lane)
{
    // issue next tile's mask loads (8 instr, 4x256B segments each)
    f32x4 sr[8];
#pragma unroll
    for (int p = 0; p < 8; ++p)
        sr[p] = *(const f32x4*)&Sg[(size_t)p * 4 * NPTS + (size_t)ktn * 64];

    // QK^T swapped for both q-frags: sacc[f][kb][r] = score[key][q=f*16+l15]
    f32x4 sacc0[4], sacc1[4];
    __builtin_amdgcn_s_setprio(1);
#pragma unroll
    for (int kb = 0; kb < 4; ++kb) {
        const ushort_t* kp = Kh + (size_t)(kt * 4 + kb) * 1024 + lane * 8;
        bf16x8 kf0 = *(const bf16x8*)kp;
        bf16x8 kf1 = *(const bf16x8*)(kp + 512);
        f32x4 z0 = (f32x4){0.f, 0.f, 0.f, 0.f};
        z0 = __builtin_amdgcn_mfma_f32_16x16x32_bf16(kf0, qf[0][0], z0, 0, 0, 0);
        z0 = __builtin_amdgcn_mfma_f32_16x16x32_bf16(kf1, qf[0][1], z0, 0, 0, 0);
        sacc0[kb] = z0;
        f32x4 z1 = (f32x4){0.f, 0.f, 0.f, 0.f};
        z1 = __builtin_amdgcn_mfma_f32_16x16x32_bf16(kf0, qf[1][0], z1, 0, 0, 0);
        z1 = __builtin_amdgcn_mfma_f32_16x16x32_bf16(kf1, qf[1][1], z1, 0, 0, 0);
        sacc1[kb] = z1;
    }
    __builtin_amdgcn_s_setprio(0);

    // issue V loads (shared by both fragments)
    bf16x8 vf[8];
    const ushort_t* vb = Vh + (size_t)kt * 4096 + lane * 8;
#pragma unroll
    for (int mm = 0; mm < 2; ++mm)
#pragma unroll
        for (int db = 0; db < 4; ++db)
            vf[mm * 4 + db] = *(const bf16x8*)(vb + db * 1024 + mm * 512);

    // p = exp(score * mask), both fragments; pack (HW cvt) -> P_lds
    float ts0 = 0.0f, ts1 = 0.0f;
#pragma unroll
    for (int kb = 0; kb < 4; ++kb) {
        unsigned a0 = *(const unsigned*)&Sw[l15][kb * 16 + lhi * 4];
        unsigned a1 = *(const unsigned*)&Sw[l15][kb * 16 + lhi * 4 + 2];
        unsigned b0 = *(const unsigned*)&Sw[16 + l15][kb * 16 + lhi * 4];
        unsigned b1 = *(const unsigned*)&Sw[16 + l15][kb * 16 + lhi * 4 + 2];
        float p00 = __expf(sacc0[kb][0] * bf2f((ushort_t)(a0 & 0xFFFF)));
        float p01 = __expf(sacc0[kb][1] * bf2f((ushort_t)(a0 >> 16)));
        float p02 = __expf(sacc0[kb][2] * bf2f((ushort_t)(a1 & 0xFFFF)));
        float p03 = __expf(sacc0[kb][3] * bf2f((ushort_t)(a1 >> 16)));
        float p10 = __expf(sacc1[kb][0] * bf2f((ushort_t)(b0 & 0xFFFF)));
        float p11 = __expf(sacc1[kb][1] * bf2f((ushort_t)(b0 >> 16)));
        float p12 = __expf(sacc1[kb][2] * bf2f((ushort_t)(b1 & 0xFFFF)));
        float p13 = __expf(sacc1[kb][3] * bf2f((ushort_t)(b1 >> 16)));
        ts0 += (p00 + p01) + (p02 + p03);
        ts1 += (p10 + p11) + (p12 + p13);
        *(unsigned*)&Pw[l15][kb * 16 + lhi * 4]          = cvt_pk(p00, p01);
        *(unsigned*)&Pw[l15][kb * 16 + lhi * 4 + 2]      = cvt_pk(p02, p03);
        *(unsigned*)&Pw[16 + l15][kb * 16 + lhi * 4]     = cvt_pk(p10, p11);
        *(unsigned*)&Pw[16 + l15][kb * 16 + lhi * 4 + 2] = cvt_pk(p12, p13);
    }
    lrun[0] += ts0;
    lrun[1] += ts1;

    // store next tile's mask (all Sw reads done; sr regs die here)
#pragma unroll
    for (int p = 0; p < 8; ++p) {
        *(unsigned*)&Sw[p * 4 + lhi][l15 * 4]     = cvt_pk(sr[p][0], sr[p][1]);
        *(unsigned*)&Sw[p * 4 + lhi][l15 * 4 + 2] = cvt_pk(sr[p][2], sr[p][3]);
    }

    // PV: mfma(A=V row=d, B=P col=q), both fragments share vf
    __builtin_amdgcn_s_setprio(1);
#pragma unroll
    for (int mm = 0; mm < 2; ++mm) {
        bf16x8 pf0 = *(const bf16x8*)&Pw[l15][mm * 32 + lhi * 8];
        bf16x8 pf1 = *(const bf16x8*)&Pw[16 + l15][mm * 32 + lhi * 8];
#pragma unroll
        for (int db = 0; db < 4; ++db) {
            macc[0][db] = __builtin_amdgcn_mfma_f32_16x16x32_bf16(vf[mm * 4 + db], pf0, macc[0][db], 0, 0, 0);
            macc[1][db] = __builtin_amdgcn_mfma_f32_16x16x32_bf16(vf[mm * 4 + db], pf1, macc[1][db], 0, 0, 0);
        }
    }
    __builtin_amdgcn_s_setprio(0);
}

// ---------------------------------------------------------------------------
// MFMA flash attention: 32 queries/warp, per-head blocks, key-split 8,
// fragment-major K/V/Q, in-kernel coalesced S staging, HW bf16 converts.
// Grid (32, NHEAD, KSPLIT); block 256 (4 warps x 32q = 128 q/block).
// ---------------------------------------------------------------------------
__global__ __launch_bounds__(256, 3) void attn_mfma(
    const ushort_t* __restrict__ Qf, const ushort_t* __restrict__ Kf,
    const ushort_t* __restrict__ Vf, const float* __restrict__ S,
    ushort_t* __restrict__ pacc, float* __restrict__ pl)
{
    __shared__ __align__(16) ushort_t P_lds[4][32][72];   // 18432 B
    __shared__ __align__(16) ushort_t S_lds[4][32][72];   // 18432 B

    const int tid  = threadIdx.x;
    const int w    = tid >> 6;
    const int lane = tid & 63;
    const int l15  = lane & 15;
    const int lhi  = lane >> 4;
    const int h    = blockIdx.y;
    const int ks   = blockIdx.z;
    const int q0   = blockIdx.x * 128 + w * 32;
    const int ktb  = ks * (KCHUNK / 64);

    const ushort_t* Kh = Kf + (size_t)h * HSTRIDE;
    const ushort_t* Vh = Vf + (size_t)h * HSTRIDE;
    const float* Sg = S + (size_t)(q0 + lhi) * NPTS + l15 * 4;
    ushort_t (* __restrict__ Pw)[72] = P_lds[w];
    ushort_t (* __restrict__ Sw)[72] = S_lds[w];

    // Q fragments for both 16q groups
    bf16x8 qf[2][2];
#pragma unroll
    for (int f = 0; f < 2; ++f) {
        const ushort_t* qp = Qf + (size_t)h * HSTRIDE
                           + (size_t)((q0 + f * 16) >> 4) * 1024 + lane * 8;
        qf[f][0] = *(const bf16x8*)qp;
        qf[f][1] = *(const bf16x8*)(qp + 512);
    }

    f32x4 macc[2][4];
#pragma unroll
    for (int f = 0; f < 2; ++f)
#pragma unroll
        for (int db = 0; db < 4; ++db) macc[f][db] = (f32x4){0.f, 0.f, 0.f, 0.f};
    float lrun[2] = {0.0f, 0.0f};

    // prologue: stage mask tile ktb
    {
#pragma unroll
        for (int p = 0; p < 8; ++p) {
            f32x4 t = *(const f32x4*)&Sg[(size_t)p * 4 * NPTS + (size_t)ktb * 64];
            *(unsigned*)&Sw[p * 4 + lhi][l15 * 4]     = cvt_pk(t[0], t[1]);
            *(unsigned*)&Sw[p * 4 + lhi][l15 * 4 + 2] = cvt_pk(t[2], t[3]);
        }
    }

    // 8 tiles; prefetch distance 1 (wrap on last is harmless)
    for (int kt = ktb; kt < ktb + 8; ++kt) {
        const int ktn = (kt + 1 < ktb + 8) ? kt + 1 : ktb;
        attn_tile(kt, ktn, Sg, Kh, Vh, qf, Sw, macc, lrun, Pw, l15, lhi, lane);
    }

    // deferred cross-group l reduction (once per block)
#pragma unroll
    for (int f = 0; f < 2; ++f) {
        lrun[f] += __shfl_xor(lrun[f], 16);
        lrun[f] += __shfl_xor(lrun[f], 32);
    }

    // store unnormalized partials for both fragments
    const size_t pb = ((size_t)ks * NHEAD + h) * NPTS;
#pragma unroll
    for (int f = 0; f < 2; ++f) {
        ushort_t* prow = pacc + (pb + q0 + f * 16 + l15) * DHEAD;
#pragma unroll
        for (int db = 0; db < 4; ++db) {
            *(unsigned*)&prow[db * 16 + lhi * 4]     = cvt_pk(macc[f][db][0], macc[f][db][1]);
            *(unsigned*)&prow[db * 16 + lhi * 4 + 2] = cvt_pk(macc[f][db][2], macc[f][db][3]);
        }
    }
    if (lane < 16) {
        pl[pb + q0 + lane]      = lrun[0];
        pl[pb + q0 + 16 + lane] = lrun[1];
    }
}

// ---------------------------------------------------------------------------
// Merge KSPLIT partials (common scale) -> msgT [N][256] bf16.
// ---------------------------------------------------------------------------
__global__ __launch_bounds__(256) void attn_merge(
    const ushort_t* __restrict__ pacc, const float* __restrict__ pl,
    ushort_t* __restrict__ msgT)
{
    const int h = blockIdx.y;
    const int q = blockIdx.x * 64 + (threadIdx.x >> 2);
    const int d0 = (threadIdx.x & 3) * 16;

    float ls = 0.0f;
#pragma unroll
    for (int ks = 0; ks < KSPLIT; ++ks)
        ls += pl[((size_t)ks * NHEAD + h) * NPTS + q];
    float inv = 1.0f / ls;

    float out[16];
#pragma unroll
    for (int j = 0; j < 16; ++j) out[j] = 0.0f;
#pragma unroll
    for (int ks = 0; ks < KSPLIT; ++ks) {
        const ushort_t* ap = pacc + (((size_t)ks * NHEAD + h) * NPTS + q) * DHEAD + d0;
        bf16x8 v0 = *(const bf16x8*)ap;
        bf16x8 v1 = *(const bf16x8*)(ap + 8);
#pragma unroll
        for (int j = 0; j < 8; ++j) {
            out[j]     += bf2f((ushort_t)v0[j]);
            out[8 + j] += bf2f((ushort_t)v1[j]);
        }
    }
    unsigned o[8];
#pragma unroll
    for (int j = 0; j < 4; ++j) {
        o[j]     = cvt_pk(out[j * 2] * inv,     out[j * 2 + 1] * inv);
        o[4 + j] = cvt_pk(out[8 + j * 2] * inv, out[8 + j * 2 + 1] * inv);
    }
    unsigned* op = (unsigned*)(msgT + (size_t)q * D_CH + h * DHEAD + d0);
    *(uint4*)op       = make_uint4(o[0], o[1], o[2], o[3]);
    *(uint4*)(op + 4) = make_uint4(o[4], o[5], o[6], o[7]);
}

// ---------------------------------------------------------------------------
extern "C" void kernel_launch(void* const* d_in, const int* in_sizes, int n_in,
                              void* d_out, int out_size, void* d_ws, size_t ws_size,
                              hipStream_t stream) {
    const float* x  = (const float*)d_in[0];
    const float* S  = (const float*)d_in[1];
    const float* Wq = (const float*)d_in[2];
    const float* bq = (const float*)d_in[3];
    const float* Wk = (const float*)d_in[4];
    const float* bk = (const float*)d_in[5];
    const float* Wv = (const float*)d_in[6];
    const float* bv = (const float*)d_in[7];
    const float* W1 = (const float*)d_in[8];
    const float* b1 = (const float*)d_in[9];
    const float* g1 = (const float*)d_in[10];
    const float* be1= (const float*)d_in[11];
    const float* W2 = (const float*)d_in[12];
    const float* b2 = (const float*)d_in[13];
    const float* g2 = (const float*)d_in[14];
    const float* be2= (const float*)d_in[15];
    const float* W3 = (const float*)d_in[16];
    const float* b3 = (const float*)d_in[17];

    char* ws = (char*)d_ws;
    const size_t MB = 1024 * 1024;
    ushort_t* xT   = (ushort_t*)(ws);                        // 2 MB
    ushort_t* Qf   = (ushort_t*)(ws + 2 * MB);               // 2 MB
    ushort_t* Kf   = (ushort_t*)(ws + 4 * MB);               // 2 MB
    ushort_t* Vf   = (ushort_t*)(ws + 6 * MB);               // 2 MB
    ushort_t* pacc = (ushort_t*)(ws + 8 * MB);               // 16 MB
    float*    pl   = (float*)   (ws + 24 * MB);              // 512 KB
    ushort_t* msgT = (ushort_t*)(ws + 25 * MB);              // 2 MB
    ushort_t* h1T  = (ushort_t*)(ws + 27 * MB);              // 1 MB
    ushort_t* h2T  = (ushort_t*)(ws + 28 * MB);              // 1 MB

    transpose_cast<<<dim3(64, 4), 256, 0, stream>>>(x, xT);
    gemm_qkv<<<dim3(64, 4, 3), 256, 0, stream>>>(Wq, bq, Wk, bk, Wv, bv, xT, Qf, Kf, Vf);

    attn_mfma<<<dim3(32, NHEAD, KSPLIT), 256, 0, stream>>>(Qf, Kf, Vf, S, pacc, pl);
    attn_merge<<<dim3(64, NHEAD), 256, 0, stream>>>(pacc, pl, msgT);

    gemm_mfma32<<<dim3(64, 4), 256, 0, stream>>>(W1, msgT, h1T, 128, NPTS, 256, b1, g1, be1, 1, nullptr, 3);
    gemm_mfma32<<<dim3(64, 4), 256, 0, stream>>>(W2, h1T, h2T, 128, NPTS, 128, b2, g2, be2, 1, nullptr, 3);
    gemm_mfma32<<<dim3(64, 8), 256, 0, stream>>>(W3, h2T, d_out, 256, NPTS, 128, b3, nullptr, nullptr, 0, x, 0);
}

// Round 17
// 98.375 us; speedup vs baseline: 1.2788x; 1.0343x over previous
//
#include <hip/hip_runtime.h>
#include <hip/hip_bf16.h>
#include <math.h>

#define D_CH   256
#define NHEAD  4
#define DHEAD  64
#define NPTS   4096
#define KSPLIT 8
#define KCHUNK (NPTS / KSPLIT)          // 512 keys = 8 tiles of 64
#define BN_RSQ 0.99999500003749963f     // 1/sqrt(1 + 1e-5)
#define HSTRIDE 262144                  // 4096*64 ushorts per head

typedef __attribute__((ext_vector_type(4))) float f32x4;
typedef __attribute__((ext_vector_type(8))) short bf16x8;
typedef unsigned short ushort_t;

__device__ __forceinline__ ushort_t f2bf(float x) {
    unsigned int b = __float_as_uint(x);
    return (ushort_t)((b + 0x7FFF + ((b >> 16) & 1)) >> 16);  // RNE (scalar fallback)
}
__device__ __forceinline__ float bf2f(ushort_t u) {
    return __uint_as_float(((unsigned int)u) << 16);
}
// HW packed f32x2 -> bf16x2 (RNE), single VALU op (T12 primitive, m240)
__device__ __forceinline__ unsigned cvt_pk(float lo, float hi) {
    unsigned r;
    asm("v_cvt_pk_bf16_f32 %0, %1, %2" : "=v"(r) : "v"(lo), "v"(hi));
    return r;
}

// ---------------------------------------------------------------------------
// prep: transpose-cast x [256][4096] f32 -> xT [4096][256] bf16
// ---------------------------------------------------------------------------
__global__ __launch_bounds__(256) void transpose_cast(
    const float* __restrict__ x, ushort_t* __restrict__ xT)
{
    __shared__ float xs[64][65];
    const int tid = threadIdx.x;
    const int n0 = blockIdx.x * 64, k0 = blockIdx.y * 64;
#pragma unroll
    for (int p = 0; p < 16; ++p) {
        int kk = p * 4 + (tid >> 6), nn = tid & 63;
        xs[kk][nn] = x[(size_t)(k0 + kk) * NPTS + n0 + nn];
    }
    __syncthreads();
#pragma unroll
    for (int p = 0; p < 16; ++p) {
        int nn = p * 4 + (tid >> 6), kk = tid & 63;
        xT[(size_t)(n0 + nn) * D_CH + k0 + kk] = f2bf(xs[kk][nn]);
    }
}

// ---------------------------------------------------------------------------
// Shared MFMA GEMM tile body (global A f32 -> cvt_pk bf16): acc = A*Bt^T.
// Warp tile 32(m) x 32(n) at (m0, n0). Bt is [N][K] bf16.
// ---------------------------------------------------------------------------
__device__ __forceinline__ void gemm_tile_body(
    const float* __restrict__ A, const ushort_t* __restrict__ Bt,
    int K, int m0, int n0, int l15, int lhi, f32x4 acc[2][2])
{
#pragma unroll
    for (int i = 0; i < 2; ++i)
#pragma unroll
        for (int j = 0; j < 2; ++j) acc[i][j] = (f32x4){0.f, 0.f, 0.f, 0.f};

    for (int k0 = 0; k0 < K; k0 += 32) {
        bf16x8 af[2], bfr[2];
#pragma unroll
        for (int mf = 0; mf < 2; ++mf) {
            const float* ap = A + (size_t)(m0 + mf * 16 + l15) * K + k0 + lhi * 8;
            float4 a0 = *(const float4*)ap;
            float4 a1 = *(const float4*)(ap + 4);
            unsigned* tp = (unsigned*)&af[mf];
            tp[0] = cvt_pk(a0.x, a0.y);
            tp[1] = cvt_pk(a0.z, a0.w);
            tp[2] = cvt_pk(a1.x, a1.y);
            tp[3] = cvt_pk(a1.z, a1.w);
        }
#pragma unroll
        for (int nf = 0; nf < 2; ++nf)
            bfr[nf] = *(const bf16x8*)&Bt[(size_t)(n0 + nf * 16 + l15) * K + k0 + lhi * 8];
#pragma unroll
        for (int mf = 0; mf < 2; ++mf)
#pragma unroll
            for (int nf = 0; nf < 2; ++nf)
                acc[mf][nf] = __builtin_amdgcn_mfma_f32_16x16x32_bf16(af[mf], bfr[nf], acc[mf][nf], 0, 0, 0);
    }
}

// ---------------------------------------------------------------------------
// Fused QKV projection -> fragment-major layouts (0.125 folded into Q).
// ---------------------------------------------------------------------------
__global__ __launch_bounds__(256) void gemm_qkv(
    const float* __restrict__ Wq, const float* __restrict__ bq,
    const float* __restrict__ Wk, const float* __restrict__ bk,
    const float* __restrict__ Wv, const float* __restrict__ bv,
    const ushort_t* __restrict__ xT,
    ushort_t* __restrict__ Qf, ushort_t* __restrict__ Kf, ushort_t* __restrict__ Vf)
{
    const int tid = threadIdx.x;
    const int w = tid >> 6, lane = tid & 63, l15 = lane & 15, lhi = lane >> 4;
    const int wm = w >> 1, wn = w & 1;
    const int m0 = blockIdx.y * 64 + wm * 32;
    const int n0 = blockIdx.x * 64 + wn * 32;
    const int z = blockIdx.z;

    const float* A    = (z == 0) ? Wq : (z == 1) ? Wk : Wv;
    const float* bias = (z == 0) ? bq : (z == 1) ? bk : bv;
    ushort_t* dst     = (z == 0) ? Qf : (z == 1) ? Kf : Vf;
    const float scl   = (z == 0) ? 0.125f : 1.0f;

    f32x4 acc[2][2];
    gemm_tile_body(A, xT, D_CH, m0, n0, l15, lhi, acc);

#pragma unroll
    for (int mf = 0; mf < 2; ++mf) {
#pragma unroll
        for (int r = 0; r < 4; ++r) {
            int m = m0 + mf * 16 + lhi * 4 + r;
            int head = m >> 6, dch = m & 63;
            float bi = bias[m];
#pragma unroll
            for (int nf = 0; nf < 2; ++nf) {
                int n = n0 + nf * 16 + l15;
                float v = (acc[mf][nf][r] + bi) * scl;
                size_t idx;
                if (z < 2)
                    idx = (size_t)head * HSTRIDE + (size_t)(n >> 4) * 1024 + (dch >> 5) * 512
                        + (((dch >> 3) & 3) * 16 + (n & 15)) * 8 + (dch & 7);
                else
                    idx = (size_t)head * HSTRIDE + (size_t)(n >> 6) * 4096 + (dch >> 4) * 1024
                        + ((n >> 5) & 1) * 512 + (((n >> 3) & 3) * 16 + (dch & 15)) * 8 + (n & 7);
                dst[idx] = (ushort_t)(cvt_pk(v, v) & 0xFFFF);
            }
        }
    }
}

// ---------------------------------------------------------------------------
// One 64-key attention tile (unchanged from r15): two q-fragments/warp,
// no-max softmax, single-buffered bf16 mask staging, HW cvt_pk, setprio.
// ---------------------------------------------------------------------------
__device__ __forceinline__ void attn_tile(
    int kt, int ktn, const float* __restrict__ Sg,
    const ushort_t* __restrict__ Kh, const ushort_t* __restrict__ Vh,
    const bf16x8 (&qf)[2][2],
    ushort_t (* __restrict__ Sw)[72],
    f32x4 (&macc)[2][4], float (&lrun)[2],
    ushort_t (* __restrict__ Pw)[72], int l15, int lhi, int lane)
{
    // issue next tile's mask loads (8 instr, 4x256B segments each)
    f32x4 sr[8];
#pragma unroll
    for (int p = 0; p < 8; ++p)
        sr[p] = *(const f32x4*)&Sg[(size_t)p * 4 * NPTS + (size_t)ktn * 64];

    // QK^T swapped for both q-frags: sacc[f][kb][r] = score[key][q=f*16+l15]
    f32x4 sacc0[4], sacc1[4];
    __builtin_amdgcn_s_setprio(1);
#pragma unroll
    for (int kb = 0; kb < 4; ++kb) {
        const ushort_t* kp = Kh + (size_t)(kt * 4 + kb) * 1024 + lane * 8;
        bf16x8 kf0 = *(const bf16x8*)kp;
        bf16x8 kf1 = *(const bf16x8*)(kp + 512);
        f32x4 z0 = (f32x4){0.f, 0.f, 0.f, 0.f};
        z0 = __builtin_amdgcn_mfma_f32_16x16x32_bf16(kf0, qf[0][0], z0, 0, 0, 0);
        z0 = __builtin_amdgcn_mfma_f32_16x16x32_bf16(kf1, qf[0][1], z0, 0, 0, 0);
        sacc0[kb] = z0;
        f32x4 z1 = (f32x4){0.f, 0.f, 0.f, 0.f};
        z1 = __builtin_amdgcn_mfma_f32_16x16x32_bf16(kf0, qf[1][0], z1, 0, 0, 0);
        z1 = __builtin_amdgcn_mfma_f32_16x16x32_bf16(kf1, qf[1][1], z1, 0, 0, 0);
        sacc1[kb] = z1;
    }
    __builtin_amdgcn_s_setprio(0);

    // issue V loads (shared by both fragments)
    bf16x8 vf[8];
    const ushort_t* vb = Vh + (size_t)kt * 4096 + lane * 8;
#pragma unroll
    for (int mm = 0; mm < 2; ++mm)
#pragma unroll
        for (int db = 0; db < 4; ++db)
            vf[mm * 4 + db] = *(const bf16x8*)(vb + db * 1024 + mm * 512);

    // p = exp(score * mask), both fragments; pack (HW cvt) -> P_lds
    float ts0 = 0.0f, ts1 = 0.0f;
#pragma unroll
    for (int kb = 0; kb < 4; ++kb) {
        unsigned a0 = *(const unsigned*)&Sw[l15][kb * 16 + lhi * 4];
        unsigned a1 = *(const unsigned*)&Sw[l15][kb * 16 + lhi * 4 + 2];
        unsigned b0 = *(const unsigned*)&Sw[16 + l15][kb * 16 + lhi * 4];
        unsigned b1 = *(const unsigned*)&Sw[16 + l15][kb * 16 + lhi * 4 + 2];
        float p00 = __expf(sacc0[kb][0] * bf2f((ushort_t)(a0 & 0xFFFF)));
        float p01 = __expf(sacc0[kb][1] * bf2f((ushort_t)(a0 >> 16)));
        float p02 = __expf(sacc0[kb][2] * bf2f((ushort_t)(a1 & 0xFFFF)));
        float p03 = __expf(sacc0[kb][3] * bf2f((ushort_t)(a1 >> 16)));
        float p10 = __expf(sacc1[kb][0] * bf2f((ushort_t)(b0 & 0xFFFF)));
        float p11 = __expf(sacc1[kb][1] * bf2f((ushort_t)(b0 >> 16)));
        float p12 = __expf(sacc1[kb][2] * bf2f((ushort_t)(b1 & 0xFFFF)));
        float p13 = __expf(sacc1[kb][3] * bf2f((ushort_t)(b1 >> 16)));
        ts0 += (p00 + p01) + (p02 + p03);
        ts1 += (p10 + p11) + (p12 + p13);
        *(unsigned*)&Pw[l15][kb * 16 + lhi * 4]          = cvt_pk(p00, p01);
        *(unsigned*)&Pw[l15][kb * 16 + lhi * 4 + 2]      = cvt_pk(p02, p03);
        *(unsigned*)&Pw[16 + l15][kb * 16 + lhi * 4]     = cvt_pk(p10, p11);
        *(unsigned*)&Pw[16 + l15][kb * 16 + lhi * 4 + 2] = cvt_pk(p12, p13);
    }
    lrun[0] += ts0;
    lrun[1] += ts1;

    // store next tile's mask (all Sw reads done; sr regs die here)
#pragma unroll
    for (int p = 0; p < 8; ++p) {
        *(unsigned*)&Sw[p * 4 + lhi][l15 * 4]     = cvt_pk(sr[p][0], sr[p][1]);
        *(unsigned*)&Sw[p * 4 + lhi][l15 * 4 + 2] = cvt_pk(sr[p][2], sr[p][3]);
    }

    // PV: mfma(A=V row=d, B=P col=q), both fragments share vf
    __builtin_amdgcn_s_setprio(1);
#pragma unroll
    for (int mm = 0; mm < 2; ++mm) {
        bf16x8 pf0 = *(const bf16x8*)&Pw[l15][mm * 32 + lhi * 8];
        bf16x8 pf1 = *(const bf16x8*)&Pw[16 + l15][mm * 32 + lhi * 8];
#pragma unroll
        for (int db = 0; db < 4; ++db) {
            macc[0][db] = __builtin_amdgcn_mfma_f32_16x16x32_bf16(vf[mm * 4 + db], pf0, macc[0][db], 0, 0, 0);
            macc[1][db] = __builtin_amdgcn_mfma_f32_16x16x32_bf16(vf[mm * 4 + db], pf1, macc[1][db], 0, 0, 0);
        }
    }
    __builtin_amdgcn_s_setprio(0);
}

// ---------------------------------------------------------------------------
// MFMA flash attention (unchanged from r15): 32 q/warp, per-head blocks,
// key-split 8. Grid (32, NHEAD, KSPLIT); block 256.
// ---------------------------------------------------------------------------
__global__ __launch_bounds__(256, 3) void attn_mfma(
    const ushort_t* __restrict__ Qf, const ushort_t* __restrict__ Kf,
    const ushort_t* __restrict__ Vf, const float* __restrict__ S,
    ushort_t* __restrict__ pacc, float* __restrict__ pl)
{
    __shared__ __align__(16) ushort_t P_lds[4][32][72];   // 18432 B
    __shared__ __align__(16) ushort_t S_lds[4][32][72];   // 18432 B

    const int tid  = threadIdx.x;
    const int w    = tid >> 6;
    const int lane = tid & 63;
    const int l15  = lane & 15;
    const int lhi  = lane >> 4;
    const int h    = blockIdx.y;
    const int ks   = blockIdx.z;
    const int q0   = blockIdx.x * 128 + w * 32;
    const int ktb  = ks * (KCHUNK / 64);

    const ushort_t* Kh = Kf + (size_t)h * HSTRIDE;
    const ushort_t* Vh = Vf + (size_t)h * HSTRIDE;
    const float* Sg = S + (size_t)(q0 + lhi) * NPTS + l15 * 4;
    ushort_t (* __restrict__ Pw)[72] = P_lds[w];
    ushort_t (* __restrict__ Sw)[72] = S_lds[w];

    bf16x8 qf[2][2];
#pragma unroll
    for (int f = 0; f < 2; ++f) {
        const ushort_t* qp = Qf + (size_t)h * HSTRIDE
                           + (size_t)((q0 + f * 16) >> 4) * 1024 + lane * 8;
        qf[f][0] = *(const bf16x8*)qp;
        qf[f][1] = *(const bf16x8*)(qp + 512);
    }

    f32x4 macc[2][4];
#pragma unroll
    for (int f = 0; f < 2; ++f)
#pragma unroll
        for (int db = 0; db < 4; ++db) macc[f][db] = (f32x4){0.f, 0.f, 0.f, 0.f};
    float lrun[2] = {0.0f, 0.0f};

    // prologue: stage mask tile ktb
    {
#pragma unroll
        for (int p = 0; p < 8; ++p) {
            f32x4 t = *(const f32x4*)&Sg[(size_t)p * 4 * NPTS + (size_t)ktb * 64];
            *(unsigned*)&Sw[p * 4 + lhi][l15 * 4]     = cvt_pk(t[0], t[1]);
            *(unsigned*)&Sw[p * 4 + lhi][l15 * 4 + 2] = cvt_pk(t[2], t[3]);
        }
    }

    // 8 tiles; prefetch distance 1 (wrap on last is harmless)
    for (int kt = ktb; kt < ktb + 8; ++kt) {
        const int ktn = (kt + 1 < ktb + 8) ? kt + 1 : ktb;
        attn_tile(kt, ktn, Sg, Kh, Vh, qf, Sw, macc, lrun, Pw, l15, lhi, lane);
    }

    // deferred cross-group l reduction (once per block)
#pragma unroll
    for (int f = 0; f < 2; ++f) {
        lrun[f] += __shfl_xor(lrun[f], 16);
        lrun[f] += __shfl_xor(lrun[f], 32);
    }

    // store unnormalized partials for both fragments
    const size_t pb = ((size_t)ks * NHEAD + h) * NPTS;
#pragma unroll
    for (int f = 0; f < 2; ++f) {
        ushort_t* prow = pacc + (pb + q0 + f * 16 + l15) * DHEAD;
#pragma unroll
        for (int db = 0; db < 4; ++db) {
            *(unsigned*)&prow[db * 16 + lhi * 4]     = cvt_pk(macc[f][db][0], macc[f][db][1]);
            *(unsigned*)&prow[db * 16 + lhi * 4 + 2] = cvt_pk(macc[f][db][2], macc[f][db][3]);
        }
    }
    if (lane < 16) {
        pl[pb + q0 + lane]      = lrun[0];
        pl[pb + q0 + 16 + lane] = lrun[1];
    }
}

// ---------------------------------------------------------------------------
// Merge KSPLIT partials (common scale) -> msgT [N][256] bf16 (r15 verbatim).
// ---------------------------------------------------------------------------
__global__ __launch_bounds__(256) void attn_merge(
    const ushort_t* __restrict__ pacc, const float* __restrict__ pl,
    ushort_t* __restrict__ msgT)
{
    const int h = blockIdx.y;
    const int q = blockIdx.x * 64 + (threadIdx.x >> 2);
    const int d0 = (threadIdx.x & 3) * 16;

    float ls = 0.0f;
#pragma unroll
    for (int ks = 0; ks < KSPLIT; ++ks)
        ls += pl[((size_t)ks * NHEAD + h) * NPTS + q];
    float inv = 1.0f / ls;

    float out[16];
#pragma unroll
    for (int j = 0; j < 16; ++j) out[j] = 0.0f;
#pragma unroll
    for (int ks = 0; ks < KSPLIT; ++ks) {
        const ushort_t* ap = pacc + (((size_t)ks * NHEAD + h) * NPTS + q) * DHEAD + d0;
        bf16x8 v0 = *(const bf16x8*)ap;
        bf16x8 v1 = *(const bf16x8*)(ap + 8);
#pragma unroll
        for (int j = 0; j < 8; ++j) {
            out[j]     += bf2f((ushort_t)v0[j]);
            out[8 + j] += bf2f((ushort_t)v1[j]);
        }
    }
    unsigned o[8];
#pragma unroll
    for (int j = 0; j < 4; ++j) {
        o[j]     = cvt_pk(out[j * 2] * inv,     out[j * 2 + 1] * inv);
        o[4 + j] = cvt_pk(out[8 + j * 2] * inv, out[8 + j * 2 + 1] * inv);
    }
    unsigned* op = (unsigned*)(msgT + (size_t)q * D_CH + h * DHEAD + d0);
    *(uint4*)op       = make_uint4(o[0], o[1], o[2], o[3]);
    *(uint4*)(op + 4) = make_uint4(o[4], o[5], o[6], o[7]);
}

// ---------------------------------------------------------------------------
// FUSED MLP: the three r15 GEMMs in one kernel, phased by __syncthreads().
// Block = 32 points. Each phase is the exact r15 gemm_mfma32 pattern:
// gemm_tile_body against GLOBAL buffers (msgT/h1T/h2T), same layouts, same
// epilogues. Each block reads/writes only its own 32-point slice of h1T/h2T,
// so the block-level barrier is sufficient.
// ---------------------------------------------------------------------------
__global__ __launch_bounds__(256) void mlp_fused(
    const ushort_t* __restrict__ msgT,
    const float* __restrict__ W1, const float* __restrict__ b1,
    const float* __restrict__ g1, const float* __restrict__ be1,
    const float* __restrict__ W2, const float* __restrict__ b2,
    const float* __restrict__ g2, const float* __restrict__ be2,
    const float* __restrict__ W3, const float* __restrict__ b3,
    const float* __restrict__ x, float* __restrict__ out,
    ushort_t* __restrict__ h1T, ushort_t* __restrict__ h2T)
{
    const int tid = threadIdx.x;
    const int w = tid >> 6, lane = tid & 63, l15 = lane & 15, lhi = lane >> 4;
    const int nblk = blockIdx.x * 32;

    // --- Phase B: h1 = relu(bn1(W1 . msg)), M=128 K=256 --------------------
    {
        f32x4 acc[2][2];
        gemm_tile_body(W1, msgT + (size_t)nblk * D_CH, D_CH, w * 32, 0, l15, lhi, acc);
#pragma unroll
        for (int mf = 0; mf < 2; ++mf)
#pragma unroll
            for (int r = 0; r < 4; ++r) {
                int m = w * 32 + mf * 16 + lhi * 4 + r;
                float bi = b1[m], sc = g1[m] * BN_RSQ, sh = be1[m];
#pragma unroll
                for (int nf = 0; nf < 2; ++nf) {
                    int n = nf * 16 + l15;
                    float v = fmaxf((acc[mf][nf][r] + bi) * sc + sh, 0.0f);
                    h1T[(size_t)(nblk + n) * 128 + m] = (ushort_t)(cvt_pk(v, v) & 0xFFFF);
                }
            }
    }
    __syncthreads();

    // --- Phase C: h2 = relu(bn2(W2 . h1)), M=128 K=128 ----------------------
    {
        f32x4 acc[2][2];
        gemm_tile_body(W2, h1T + (size_t)nblk * 128, 128, w * 32, 0, l15, lhi, acc);
#pragma unroll
        for (int mf = 0; mf < 2; ++mf)
#pragma unroll
            for (int r = 0; r < 4; ++r) {
                int m = w * 32 + mf * 16 + lhi * 4 + r;
                float bi = b2[m], sc = g2[m] * BN_RSQ, sh = be2[m];
#pragma unroll
                for (int nf = 0; nf < 2; ++nf) {
                    int n = nf * 16 + l15;
                    float v = fmaxf((acc[mf][nf][r] + bi) * sc + sh, 0.0f);
                    h2T[(size_t)(nblk + n) * 128 + m] = (ushort_t)(cvt_pk(v, v) & 0xFFFF);
                }
            }
    }
    __syncthreads();

    // --- Phase D: out = x + W3 . h2, M=256 K=128 (two 32-row halves) --------
#pragma unroll
    for (int half = 0; half < 2; ++half) {
        f32x4 acc[2][2];
        const int m0 = w * 64 + half * 32;
        gemm_tile_body(W3, h2T + (size_t)nblk * 128, 128, m0, 0, l15, lhi, acc);
#pragma unroll
        for (int mf = 0; mf < 2; ++mf)
#pragma unroll
            for (int r = 0; r < 4; ++r) {
                int m = m0 + mf * 16 + lhi * 4 + r;
                float bi = b3[m];
#pragma unroll
                for (int nf = 0; nf < 2; ++nf) {
                    int n = nblk + nf * 16 + l15;
                    out[(size_t)m * NPTS + n] = acc[mf][nf][r] + bi + x[(size_t)m * NPTS + n];
                }
            }
    }
}

// ---------------------------------------------------------------------------
extern "C" void kernel_launch(void* const* d_in, const int* in_sizes, int n_in,
                              void* d_out, int out_size, void* d_ws, size_t ws_size,
                              hipStream_t stream) {
    const float* x  = (const float*)d_in[0];
    const float* S  = (const float*)d_in[1];
    const float* Wq = (const float*)d_in[2];
    const float* bq = (const float*)d_in[3];
    const float* Wk = (const float*)d_in[4];
    const float* bk = (const float*)d_in[5];
    const float* Wv = (const float*)d_in[6];
    const float* bv = (const float*)d_in[7];
    const float* W1 = (const float*)d_in[8];
    const float* b1 = (const float*)d_in[9];
    const float* g1 = (const float*)d_in[10];
    const float* be1= (const float*)d_in[11];
    const float* W2 = (const float*)d_in[12];
    const float* b2 = (const float*)d_in[13];
    const float* g2 = (const float*)d_in[14];
    const float* be2= (const float*)d_in[15];
    const float* W3 = (const float*)d_in[16];
    const float* b3 = (const float*)d_in[17];

    char* ws = (char*)d_ws;
    const size_t MB = 1024 * 1024;
    ushort_t* xT   = (ushort_t*)(ws);                        // 2 MB
    ushort_t* Qf   = (ushort_t*)(ws + 2 * MB);               // 2 MB
    ushort_t* Kf   = (ushort_t*)(ws + 4 * MB);               // 2 MB
    ushort_t* Vf   = (ushort_t*)(ws + 6 * MB);               // 2 MB
    ushort_t* pacc = (ushort_t*)(ws + 8 * MB);               // 16 MB
    float*    pl   = (float*)   (ws + 24 * MB);              // 512 KB
    ushort_t* msgT = (ushort_t*)(ws + 25 * MB);              // 2 MB
    ushort_t* h1T  = (ushort_t*)(ws + 27 * MB);              // 1 MB
    ushort_t* h2T  = (ushort_t*)(ws + 28 * MB);              // 1 MB

    transpose_cast<<<dim3(64, 4), 256, 0, stream>>>(x, xT);
    gemm_qkv<<<dim3(64, 4, 3), 256, 0, stream>>>(Wq, bq, Wk, bk, Wv, bv, xT, Qf, Kf, Vf);

    attn_mfma<<<dim3(32, NHEAD, KSPLIT), 256, 0, stream>>>(Qf, Kf, Vf, S, pacc, pl);
    attn_merge<<<dim3(64, NHEAD), 256, 0, stream>>>(pacc, pl, msgT);

    mlp_fused<<<dim3(128), 256, 0, stream>>>(msgT,
        W1, b1, g1, be1, W2, b2, g2, be2, W3, b3, x, (float*)d_out, h1T, h2T);
}

// Round 18
// 97.986 us; speedup vs baseline: 1.2839x; 1.0040x over previous
//
#include <hip/hip_runtime.h>
#include <hip/hip_bf16.h>
#include <math.h>

#define D_CH   256
#define NHEAD  4
#define DHEAD  64
#define NPTS   4096
#define KSPLIT 8
#define KCHUNK (NPTS / KSPLIT)          // 512 keys = 8 tiles of 64
#define BN_RSQ 0.99999500003749963f     // 1/sqrt(1 + 1e-5)
#define HSTRIDE 262144                  // 4096*64 ushorts per head

typedef __attribute__((ext_vector_type(4))) float f32x4;
typedef __attribute__((ext_vector_type(8))) short bf16x8;
typedef unsigned short ushort_t;

__device__ __forceinline__ ushort_t f2bf(float x) {
    unsigned int b = __float_as_uint(x);
    return (ushort_t)((b + 0x7FFF + ((b >> 16) & 1)) >> 16);  // RNE (scalar fallback)
}
__device__ __forceinline__ float bf2f(ushort_t u) {
    return __uint_as_float(((unsigned int)u) << 16);
}
// HW packed f32x2 -> bf16x2 (RNE), single VALU op (T12 primitive, m240)
__device__ __forceinline__ unsigned cvt_pk(float lo, float hi) {
    unsigned r;
    asm("v_cvt_pk_bf16_f32 %0, %1, %2" : "=v"(r) : "v"(lo), "v"(hi));
    return r;
}

// ---------------------------------------------------------------------------
// prep: transpose-cast x [256][4096] f32 -> xT [4096][256] bf16
// ---------------------------------------------------------------------------
__global__ __launch_bounds__(256) void transpose_cast(
    const float* __restrict__ x, ushort_t* __restrict__ xT)
{
    __shared__ float xs[64][65];
    const int tid = threadIdx.x;
    const int n0 = blockIdx.x * 64, k0 = blockIdx.y * 64;
#pragma unroll
    for (int p = 0; p < 16; ++p) {
        int kk = p * 4 + (tid >> 6), nn = tid & 63;
        xs[kk][nn] = x[(size_t)(k0 + kk) * NPTS + n0 + nn];
    }
    __syncthreads();
#pragma unroll
    for (int p = 0; p < 16; ++p) {
        int nn = p * 4 + (tid >> 6), kk = tid & 63;
        xT[(size_t)(n0 + nn) * D_CH + k0 + kk] = f2bf(xs[kk][nn]);
    }
}

// ---------------------------------------------------------------------------
// Shared MFMA GEMM tile body (global A f32 -> cvt_pk bf16): acc = A*Bt^T.
// Warp tile 32(m) x 32(n) at (m0, n0). Bt is [N][K] bf16.
// ---------------------------------------------------------------------------
__device__ __forceinline__ void gemm_tile_body(
    const float* __restrict__ A, const ushort_t* __restrict__ Bt,
    int K, int m0, int n0, int l15, int lhi, f32x4 acc[2][2])
{
#pragma unroll
    for (int i = 0; i < 2; ++i)
#pragma unroll
        for (int j = 0; j < 2; ++j) acc[i][j] = (f32x4){0.f, 0.f, 0.f, 0.f};

    for (int k0 = 0; k0 < K; k0 += 32) {
        bf16x8 af[2], bfr[2];
#pragma unroll
        for (int mf = 0; mf < 2; ++mf) {
            const float* ap = A + (size_t)(m0 + mf * 16 + l15) * K + k0 + lhi * 8;
            float4 a0 = *(const float4*)ap;
            float4 a1 = *(const float4*)(ap + 4);
            unsigned* tp = (unsigned*)&af[mf];
            tp[0] = cvt_pk(a0.x, a0.y);
            tp[1] = cvt_pk(a0.z, a0.w);
            tp[2] = cvt_pk(a1.x, a1.y);
            tp[3] = cvt_pk(a1.z, a1.w);
        }
#pragma unroll
        for (int nf = 0; nf < 2; ++nf)
            bfr[nf] = *(const bf16x8*)&Bt[(size_t)(n0 + nf * 16 + l15) * K + k0 + lhi * 8];
#pragma unroll
        for (int mf = 0; mf < 2; ++mf)
#pragma unroll
            for (int nf = 0; nf < 2; ++nf)
                acc[mf][nf] = __builtin_amdgcn_mfma_f32_16x16x32_bf16(af[mf], bfr[nf], acc[mf][nf], 0, 0, 0);
    }
}

// ---------------------------------------------------------------------------
// Fused QKV projection -> fragment-major layouts (0.125 folded into Q).
// ---------------------------------------------------------------------------
__global__ __launch_bounds__(256) void gemm_qkv(
    const float* __restrict__ Wq, const float* __restrict__ bq,
    const float* __restrict__ Wk, const float* __restrict__ bk,
    const float* __restrict__ Wv, const float* __restrict__ bv,
    const ushort_t* __restrict__ xT,
    ushort_t* __restrict__ Qf, ushort_t* __restrict__ Kf, ushort_t* __restrict__ Vf)
{
    const int tid = threadIdx.x;
    const int w = tid >> 6, lane = tid & 63, l15 = lane & 15, lhi = lane >> 4;
    const int wm = w >> 1, wn = w & 1;
    const int m0 = blockIdx.y * 64 + wm * 32;
    const int n0 = blockIdx.x * 64 + wn * 32;
    const int z = blockIdx.z;

    const float* A    = (z == 0) ? Wq : (z == 1) ? Wk : Wv;
    const float* bias = (z == 0) ? bq : (z == 1) ? bk : bv;
    ushort_t* dst     = (z == 0) ? Qf : (z == 1) ? Kf : Vf;
    const float scl   = (z == 0) ? 0.125f : 1.0f;

    f32x4 acc[2][2];
    gemm_tile_body(A, xT, D_CH, m0, n0, l15, lhi, acc);

#pragma unroll
    for (int mf = 0; mf < 2; ++mf) {
#pragma unroll
        for (int r = 0; r < 4; ++r) {
            int m = m0 + mf * 16 + lhi * 4 + r;
            int head = m >> 6, dch = m & 63;
            float bi = bias[m];
#pragma unroll
            for (int nf = 0; nf < 2; ++nf) {
                int n = n0 + nf * 16 + l15;
                float v = (acc[mf][nf][r] + bi) * scl;
                size_t idx;
                if (z < 2)
                    idx = (size_t)head * HSTRIDE + (size_t)(n >> 4) * 1024 + (dch >> 5) * 512
                        + (((dch >> 3) & 3) * 16 + (n & 15)) * 8 + (dch & 7);
                else
                    idx = (size_t)head * HSTRIDE + (size_t)(n >> 6) * 4096 + (dch >> 4) * 1024
                        + ((n >> 5) & 1) * 512 + (((n >> 3) & 3) * 16 + (dch & 15)) * 8 + (n & 7);
                dst[idx] = (ushort_t)(cvt_pk(v, v) & 0xFFFF);
            }
        }
    }
}

// ---------------------------------------------------------------------------
// One 64-key attention tile (unchanged from r15/r17).
// ---------------------------------------------------------------------------
__device__ __forceinline__ void attn_tile(
    int kt, int ktn, const float* __restrict__ Sg,
    const ushort_t* __restrict__ Kh, const ushort_t* __restrict__ Vh,
    const bf16x8 (&qf)[2][2],
    ushort_t (* __restrict__ Sw)[72],
    f32x4 (&macc)[2][4], float (&lrun)[2],
    ushort_t (* __restrict__ Pw)[72], int l15, int lhi, int lane)
{
    // issue next tile's mask loads (8 instr, 4x256B segments each)
    f32x4 sr[8];
#pragma unroll
    for (int p = 0; p < 8; ++p)
        sr[p] = *(const f32x4*)&Sg[(size_t)p * 4 * NPTS + (size_t)ktn * 64];

    // QK^T swapped for both q-frags: sacc[f][kb][r] = score[key][q=f*16+l15]
    f32x4 sacc0[4], sacc1[4];
    __builtin_amdgcn_s_setprio(1);
#pragma unroll
    for (int kb = 0; kb < 4; ++kb) {
        const ushort_t* kp = Kh + (size_t)(kt * 4 + kb) * 1024 + lane * 8;
        bf16x8 kf0 = *(const bf16x8*)kp;
        bf16x8 kf1 = *(const bf16x8*)(kp + 512);
        f32x4 z0 = (f32x4){0.f, 0.f, 0.f, 0.f};
        z0 = __builtin_amdgcn_mfma_f32_16x16x32_bf16(kf0, qf[0][0], z0, 0, 0, 0);
        z0 = __builtin_amdgcn_mfma_f32_16x16x32_bf16(kf1, qf[0][1], z0, 0, 0, 0);
        sacc0[kb] = z0;
        f32x4 z1 = (f32x4){0.f, 0.f, 0.f, 0.f};
        z1 = __builtin_amdgcn_mfma_f32_16x16x32_bf16(kf0, qf[1][0], z1, 0, 0, 0);
        z1 = __builtin_amdgcn_mfma_f32_16x16x32_bf16(kf1, qf[1][1], z1, 0, 0, 0);
        sacc1[kb] = z1;
    }
    __builtin_amdgcn_s_setprio(0);

    // issue V loads (shared by both fragments)
    bf16x8 vf[8];
    const ushort_t* vb = Vh + (size_t)kt * 4096 + lane * 8;
#pragma unroll
    for (int mm = 0; mm < 2; ++mm)
#pragma unroll
        for (int db = 0; db < 4; ++db)
            vf[mm * 4 + db] = *(const bf16x8*)(vb + db * 1024 + mm * 512);

    // p = exp(score * mask), both fragments; pack (HW cvt) -> P_lds
    float ts0 = 0.0f, ts1 = 0.0f;
#pragma unroll
    for (int kb = 0; kb < 4; ++kb) {
        unsigned a0 = *(const unsigned*)&Sw[l15][kb * 16 + lhi * 4];
        unsigned a1 = *(const unsigned*)&Sw[l15][kb * 16 + lhi * 4 + 2];
        unsigned b0 = *(const unsigned*)&Sw[16 + l15][kb * 16 + lhi * 4];
        unsigned b1 = *(const unsigned*)&Sw[16 + l15][kb * 16 + lhi * 4 + 2];
        float p00 = __expf(sacc0[kb][0] * bf2f((ushort_t)(a0 & 0xFFFF)));
        float p01 = __expf(sacc0[kb][1] * bf2f((ushort_t)(a0 >> 16)));
        float p02 = __expf(sacc0[kb][2] * bf2f((ushort_t)(a1 & 0xFFFF)));
        float p03 = __expf(sacc0[kb][3] * bf2f((ushort_t)(a1 >> 16)));
        float p10 = __expf(sacc1[kb][0] * bf2f((ushort_t)(b0 & 0xFFFF)));
        float p11 = __expf(sacc1[kb][1] * bf2f((ushort_t)(b0 >> 16)));
        float p12 = __expf(sacc1[kb][2] * bf2f((ushort_t)(b1 & 0xFFFF)));
        float p13 = __expf(sacc1[kb][3] * bf2f((ushort_t)(b1 >> 16)));
        ts0 += (p00 + p01) + (p02 + p03);
        ts1 += (p10 + p11) + (p12 + p13);
        *(unsigned*)&Pw[l15][kb * 16 + lhi * 4]          = cvt_pk(p00, p01);
        *(unsigned*)&Pw[l15][kb * 16 + lhi * 4 + 2]      = cvt_pk(p02, p03);
        *(unsigned*)&Pw[16 + l15][kb * 16 + lhi * 4]     = cvt_pk(p10, p11);
        *(unsigned*)&Pw[16 + l15][kb * 16 + lhi * 4 + 2] = cvt_pk(p12, p13);
    }
    lrun[0] += ts0;
    lrun[1] += ts1;

    // store next tile's mask (all Sw reads done; sr regs die here)
#pragma unroll
    for (int p = 0; p < 8; ++p) {
        *(unsigned*)&Sw[p * 4 + lhi][l15 * 4]     = cvt_pk(sr[p][0], sr[p][1]);
        *(unsigned*)&Sw[p * 4 + lhi][l15 * 4 + 2] = cvt_pk(sr[p][2], sr[p][3]);
    }

    // PV: mfma(A=V row=d, B=P col=q), both fragments share vf
    __builtin_amdgcn_s_setprio(1);
#pragma unroll
    for (int mm = 0; mm < 2; ++mm) {
        bf16x8 pf0 = *(const bf16x8*)&Pw[l15][mm * 32 + lhi * 8];
        bf16x8 pf1 = *(const bf16x8*)&Pw[16 + l15][mm * 32 + lhi * 8];
#pragma unroll
        for (int db = 0; db < 4; ++db) {
            macc[0][db] = __builtin_amdgcn_mfma_f32_16x16x32_bf16(vf[mm * 4 + db], pf0, macc[0][db], 0, 0, 0);
            macc[1][db] = __builtin_amdgcn_mfma_f32_16x16x32_bf16(vf[mm * 4 + db], pf1, macc[1][db], 0, 0, 0);
        }
    }
    __builtin_amdgcn_s_setprio(0);
}

// ---------------------------------------------------------------------------
// MFMA flash attention (unchanged from r15/r17): 32 q/warp, per-head blocks,
// key-split 8. Grid (32, NHEAD, KSPLIT); block 256.
// ---------------------------------------------------------------------------
__global__ __launch_bounds__(256, 3) void attn_mfma(
    const ushort_t* __restrict__ Qf, const ushort_t* __restrict__ Kf,
    const ushort_t* __restrict__ Vf, const float* __restrict__ S,
    ushort_t* __restrict__ pacc, float* __restrict__ pl)
{
    __shared__ __align__(16) ushort_t P_lds[4][32][72];   // 18432 B
    __shared__ __align__(16) ushort_t S_lds[4][32][72];   // 18432 B

    const int tid  = threadIdx.x;
    const int w    = tid >> 6;
    const int lane = tid & 63;
    const int l15  = lane & 15;
    const int lhi  = lane >> 4;
    const int h    = blockIdx.y;
    const int ks   = blockIdx.z;
    const int q0   = blockIdx.x * 128 + w * 32;
    const int ktb  = ks * (KCHUNK / 64);

    const ushort_t* Kh = Kf + (size_t)h * HSTRIDE;
    const ushort_t* Vh = Vf + (size_t)h * HSTRIDE;
    const float* Sg = S + (size_t)(q0 + lhi) * NPTS + l15 * 4;
    ushort_t (* __restrict__ Pw)[72] = P_lds[w];
    ushort_t (* __restrict__ Sw)[72] = S_lds[w];

    bf16x8 qf[2][2];
#pragma unroll
    for (int f = 0; f < 2; ++f) {
        const ushort_t* qp = Qf + (size_t)h * HSTRIDE
                           + (size_t)((q0 + f * 16) >> 4) * 1024 + lane * 8;
        qf[f][0] = *(const bf16x8*)qp;
        qf[f][1] = *(const bf16x8*)(qp + 512);
    }

    f32x4 macc[2][4];
#pragma unroll
    for (int f = 0; f < 2; ++f)
#pragma unroll
        for (int db = 0; db < 4; ++db) macc[f][db] = (f32x4){0.f, 0.f, 0.f, 0.f};
    float lrun[2] = {0.0f, 0.0f};

    // prologue: stage mask tile ktb
    {
#pragma unroll
        for (int p = 0; p < 8; ++p) {
            f32x4 t = *(const f32x4*)&Sg[(size_t)p * 4 * NPTS + (size_t)ktb * 64];
            *(unsigned*)&Sw[p * 4 + lhi][l15 * 4]     = cvt_pk(t[0], t[1]);
            *(unsigned*)&Sw[p * 4 + lhi][l15 * 4 + 2] = cvt_pk(t[2], t[3]);
        }
    }

    // 8 tiles; prefetch distance 1 (wrap on last is harmless)
    for (int kt = ktb; kt < ktb + 8; ++kt) {
        const int ktn = (kt + 1 < ktb + 8) ? kt + 1 : ktb;
        attn_tile(kt, ktn, Sg, Kh, Vh, qf, Sw, macc, lrun, Pw, l15, lhi, lane);
    }

    // deferred cross-group l reduction (once per block)
#pragma unroll
    for (int f = 0; f < 2; ++f) {
        lrun[f] += __shfl_xor(lrun[f], 16);
        lrun[f] += __shfl_xor(lrun[f], 32);
    }

    // store unnormalized partials for both fragments
    const size_t pb = ((size_t)ks * NHEAD + h) * NPTS;
#pragma unroll
    for (int f = 0; f < 2; ++f) {
        ushort_t* prow = pacc + (pb + q0 + f * 16 + l15) * DHEAD;
#pragma unroll
        for (int db = 0; db < 4; ++db) {
            *(unsigned*)&prow[db * 16 + lhi * 4]     = cvt_pk(macc[f][db][0], macc[f][db][1]);
            *(unsigned*)&prow[db * 16 + lhi * 4 + 2] = cvt_pk(macc[f][db][2], macc[f][db][3]);
        }
    }
    if (lane < 16) {
        pl[pb + q0 + lane]      = lrun[0];
        pl[pb + q0 + 16 + lane] = lrun[1];
    }
}

// ---------------------------------------------------------------------------
// FUSED MERGE + MLP: Phase A merges the KSPLIT partials for this block's
// 32-point slice (element formulas identical to the proven attn_merge;
// thread map = 32q x 8 d-groups of 8) and writes msgT globally. Phases
// B/C/D are verbatim r17 (proven): block-local global scratch RAW across
// __syncthreads (same CU -> same L2; L1 is write-through).
// ---------------------------------------------------------------------------
__global__ __launch_bounds__(256) void mlp_fused(
    const ushort_t* __restrict__ pacc, const float* __restrict__ pl,
    ushort_t* __restrict__ msgT,
    const float* __restrict__ W1, const float* __restrict__ b1,
    const float* __restrict__ g1, const float* __restrict__ be1,
    const float* __restrict__ W2, const float* __restrict__ b2,
    const float* __restrict__ g2, const float* __restrict__ be2,
    const float* __restrict__ W3, const float* __restrict__ b3,
    const float* __restrict__ x, float* __restrict__ out,
    ushort_t* __restrict__ h1T, ushort_t* __restrict__ h2T)
{
    const int tid = threadIdx.x;
    const int w = tid >> 6, lane = tid & 63, l15 = lane & 15, lhi = lane >> 4;
    const int nblk = blockIdx.x * 32;

    // --- Phase A: merge partials -> msgT (this block's 32 rows) ------------
    {
        const int ql = tid >> 3;          // 0..31: local point
        const int d0 = (tid & 7) * 8;     // 0..56: channel sub-group
#pragma unroll
        for (int h = 0; h < NHEAD; ++h) {
            float ls = 0.0f;
#pragma unroll
            for (int ks = 0; ks < KSPLIT; ++ks)
                ls += pl[((size_t)ks * NHEAD + h) * NPTS + nblk + ql];
            float inv = 1.0f / ls;
            float o[8];
#pragma unroll
            for (int j = 0; j < 8; ++j) o[j] = 0.0f;
#pragma unroll
            for (int ks = 0; ks < KSPLIT; ++ks) {
                const ushort_t* ap = pacc
                    + (((size_t)ks * NHEAD + h) * NPTS + nblk + ql) * DHEAD + d0;
                bf16x8 v = *(const bf16x8*)ap;
#pragma unroll
                for (int j = 0; j < 8; ++j) o[j] += bf2f((ushort_t)v[j]);
            }
            unsigned* dp = (unsigned*)(msgT + (size_t)(nblk + ql) * D_CH + h * 64 + d0);
            dp[0] = cvt_pk(o[0] * inv, o[1] * inv);
            dp[1] = cvt_pk(o[2] * inv, o[3] * inv);
            dp[2] = cvt_pk(o[4] * inv, o[5] * inv);
            dp[3] = cvt_pk(o[6] * inv, o[7] * inv);
        }
    }
    __syncthreads();

    // --- Phase B: h1 = relu(bn1(W1 . msg)), M=128 K=256 --------------------
    {
        f32x4 acc[2][2];
        gemm_tile_body(W1, msgT + (size_t)nblk * D_CH, D_CH, w * 32, 0, l15, lhi, acc);
#pragma unroll
        for (int mf = 0; mf < 2; ++mf)
#pragma unroll
            for (int r = 0; r < 4; ++r) {
                int m = w * 32 + mf * 16 + lhi * 4 + r;
                float bi = b1[m], sc = g1[m] * BN_RSQ, sh = be1[m];
#pragma unroll
                for (int nf = 0; nf < 2; ++nf) {
                    int n = nf * 16 + l15;
                    float v = fmaxf((acc[mf][nf][r] + bi) * sc + sh, 0.0f);
                    h1T[(size_t)(nblk + n) * 128 + m] = (ushort_t)(cvt_pk(v, v) & 0xFFFF);
                }
            }
    }
    __syncthreads();

    // --- Phase C: h2 = relu(bn2(W2 . h1)), M=128 K=128 ----------------------
    {
        f32x4 acc[2][2];
        gemm_tile_body(W2, h1T + (size_t)nblk * 128, 128, w * 32, 0, l15, lhi, acc);
#pragma unroll
        for (int mf = 0; mf < 2; ++mf)
#pragma unroll
            for (int r = 0; r < 4; ++r) {
                int m = w * 32 + mf * 16 + lhi * 4 + r;
                float bi = b2[m], sc = g2[m] * BN_RSQ, sh = be2[m];
#pragma unroll
                for (int nf = 0; nf < 2; ++nf) {
                    int n = nf * 16 + l15;
                    float v = fmaxf((acc[mf][nf][r] + bi) * sc + sh, 0.0f);
                    h2T[(size_t)(nblk + n) * 128 + m] = (ushort_t)(cvt_pk(v, v) & 0xFFFF);
                }
            }
    }
    __syncthreads();

    // --- Phase D: out = x + W3 . h2, M=256 K=128 (two 32-row halves) --------
#pragma unroll
    for (int half = 0; half < 2; ++half) {
        f32x4 acc[2][2];
        const int m0 = w * 64 + half * 32;
        gemm_tile_body(W3, h2T + (size_t)nblk * 128, 128, m0, 0, l15, lhi, acc);
#pragma unroll
        for (int mf = 0; mf < 2; ++mf)
#pragma unroll
            for (int r = 0; r < 4; ++r) {
                int m = m0 + mf * 16 + lhi * 4 + r;
                float bi = b3[m];
#pragma unroll
                for (int nf = 0; nf < 2; ++nf) {
                    int n = nblk + nf * 16 + l15;
                    out[(size_t)m * NPTS + n] = acc[mf][nf][r] + bi + x[(size_t)m * NPTS + n];
                }
            }
    }
}

// ---------------------------------------------------------------------------
extern "C" void kernel_launch(void* const* d_in, const int* in_sizes, int n_in,
                              void* d_out, int out_size, void* d_ws, size_t ws_size,
                              hipStream_t stream) {
    const float* x  = (const float*)d_in[0];
    const float* S  = (const float*)d_in[1];
    const float* Wq = (const float*)d_in[2];
    const float* bq = (const float*)d_in[3];
    const float* Wk = (const float*)d_in[4];
    const float* bk = (const float*)d_in[5];
    const float* Wv = (const float*)d_in[6];
    const float* bv = (const float*)d_in[7];
    const float* W1 = (const float*)d_in[8];
    const float* b1 = (const float*)d_in[9];
    const float* g1 = (const float*)d_in[10];
    const float* be1= (const float*)d_in[11];
    const float* W2 = (const float*)d_in[12];
    const float* b2 = (const float*)d_in[13];
    const float* g2 = (const float*)d_in[14];
    const float* be2= (const float*)d_in[15];
    const float* W3 = (const float*)d_in[16];
    const float* b3 = (const float*)d_in[17];

    char* ws = (char*)d_ws;
    const size_t MB = 1024 * 1024;
    ushort_t* xT   = (ushort_t*)(ws);                        // 2 MB
    ushort_t* Qf   = (ushort_t*)(ws + 2 * MB);               // 2 MB
    ushort_t* Kf   = (ushort_t*)(ws + 4 * MB);               // 2 MB
    ushort_t* Vf   = (ushort_t*)(ws + 6 * MB);               // 2 MB
    ushort_t* pacc = (ushort_t*)(ws + 8 * MB);               // 16 MB
    float*    pl   = (float*)   (ws + 24 * MB);              // 512 KB
    ushort_t* msgT = (ushort_t*)(ws + 25 * MB);              // 2 MB
    ushort_t* h1T  = (ushort_t*)(ws + 27 * MB);              // 1 MB
    ushort_t* h2T  = (ushort_t*)(ws + 28 * MB);              // 1 MB

    transpose_cast<<<dim3(64, 4), 256, 0, stream>>>(x, xT);
    gemm_qkv<<<dim3(64, 4, 3), 256, 0, stream>>>(Wq, bq, Wk, bk, Wv, bv, xT, Qf, Kf, Vf);

    attn_mfma<<<dim3(32, NHEAD, KSPLIT), 256, 0, stream>>>(Qf, Kf, Vf, S, pacc, pl);

    mlp_fused<<<dim3(128), 256, 0, stream>>>(pacc, pl, msgT,
        W1, b1, g1, be1, W2, b2, g2, be2, W3, b3, x, (float*)d_out, h1T, h2T);
}

// Round 19
// 97.792 us; speedup vs baseline: 1.2865x; 1.0020x over previous
//
#include <hip/hip_runtime.h>
#include <hip/hip_bf16.h>
#include <math.h>

#define D_CH   256
#define NHEAD  4
#define DHEAD  64
#define NPTS   4096
#define KSPLIT 8
#define KCHUNK (NPTS / KSPLIT)          // 512 keys = 8 tiles of 64
#define BN_RSQ 0.99999500003749963f     // 1/sqrt(1 + 1e-5)
#define HSTRIDE 262144                  // 4096*64 ushorts per head

typedef __attribute__((ext_vector_type(4))) float f32x4;
typedef __attribute__((ext_vector_type(8))) short bf16x8;
typedef unsigned short ushort_t;

__device__ __forceinline__ ushort_t f2bf(float x) {
    unsigned int b = __float_as_uint(x);
    return (ushort_t)((b + 0x7FFF + ((b >> 16) & 1)) >> 16);  // RNE (scalar fallback)
}
__device__ __forceinline__ float bf2f(ushort_t u) {
    return __uint_as_float(((unsigned int)u) << 16);
}
// HW packed f32x2 -> bf16x2 (RNE), single VALU op (T12 primitive, m240)
__device__ __forceinline__ unsigned cvt_pk(float lo, float hi) {
    unsigned r;
    asm("v_cvt_pk_bf16_f32 %0, %1, %2" : "=v"(r) : "v"(lo), "v"(hi));
    return r;
}

// ---------------------------------------------------------------------------
// prep: transpose-cast x [256][4096] f32 -> xT [4096][256] bf16
// ---------------------------------------------------------------------------
__global__ __launch_bounds__(256) void transpose_cast(
    const float* __restrict__ x, ushort_t* __restrict__ xT)
{
    __shared__ float xs[64][65];
    const int tid = threadIdx.x;
    const int n0 = blockIdx.x * 64, k0 = blockIdx.y * 64;
#pragma unroll
    for (int p = 0; p < 16; ++p) {
        int kk = p * 4 + (tid >> 6), nn = tid & 63;
        xs[kk][nn] = x[(size_t)(k0 + kk) * NPTS + n0 + nn];
    }
    __syncthreads();
#pragma unroll
    for (int p = 0; p < 16; ++p) {
        int nn = p * 4 + (tid >> 6), kk = tid & 63;
        xT[(size_t)(n0 + nn) * D_CH + k0 + kk] = f2bf(xs[kk][nn]);
    }
}

// ---------------------------------------------------------------------------
// Shared MFMA GEMM tile body (global A f32 -> cvt_pk bf16): acc = A*Bt^T.
// Warp tile 32(m) x 32(n) at (m0, n0). Bt is [N][K] bf16.
// ---------------------------------------------------------------------------
__device__ __forceinline__ void gemm_tile_body(
    const float* __restrict__ A, const ushort_t* __restrict__ Bt,
    int K, int m0, int n0, int l15, int lhi, f32x4 acc[2][2])
{
#pragma unroll
    for (int i = 0; i < 2; ++i)
#pragma unroll
        for (int j = 0; j < 2; ++j) acc[i][j] = (f32x4){0.f, 0.f, 0.f, 0.f};

    for (int k0 = 0; k0 < K; k0 += 32) {
        bf16x8 af[2], bfr[2];
#pragma unroll
        for (int mf = 0; mf < 2; ++mf) {
            const float* ap = A + (size_t)(m0 + mf * 16 + l15) * K + k0 + lhi * 8;
            float4 a0 = *(const float4*)ap;
            float4 a1 = *(const float4*)(ap + 4);
            unsigned* tp = (unsigned*)&af[mf];
            tp[0] = cvt_pk(a0.x, a0.y);
            tp[1] = cvt_pk(a0.z, a0.w);
            tp[2] = cvt_pk(a1.x, a1.y);
            tp[3] = cvt_pk(a1.z, a1.w);
        }
#pragma unroll
        for (int nf = 0; nf < 2; ++nf)
            bfr[nf] = *(const bf16x8*)&Bt[(size_t)(n0 + nf * 16 + l15) * K + k0 + lhi * 8];
#pragma unroll
        for (int mf = 0; mf < 2; ++mf)
#pragma unroll
            for (int nf = 0; nf < 2; ++nf)
                acc[mf][nf] = __builtin_amdgcn_mfma_f32_16x16x32_bf16(af[mf], bfr[nf], acc[mf][nf], 0, 0, 0);
    }
}

// ---------------------------------------------------------------------------
// Fused QKV projection -> fragment-major layouts (0.125 folded into Q).
// ---------------------------------------------------------------------------
__global__ __launch_bounds__(256) void gemm_qkv(
    const float* __restrict__ Wq, const float* __restrict__ bq,
    const float* __restrict__ Wk, const float* __restrict__ bk,
    const float* __restrict__ Wv, const float* __restrict__ bv,
    const ushort_t* __restrict__ xT,
    ushort_t* __restrict__ Qf, ushort_t* __restrict__ Kf, ushort_t* __restrict__ Vf)
{
    const int tid = threadIdx.x;
    const int w = tid >> 6, lane = tid & 63, l15 = lane & 15, lhi = lane >> 4;
    const int wm = w >> 1, wn = w & 1;
    const int m0 = blockIdx.y * 64 + wm * 32;
    const int n0 = blockIdx.x * 64 + wn * 32;
    const int z = blockIdx.z;

    const float* A    = (z == 0) ? Wq : (z == 1) ? Wk : Wv;
    const float* bias = (z == 0) ? bq : (z == 1) ? bk : bv;
    ushort_t* dst     = (z == 0) ? Qf : (z == 1) ? Kf : Vf;
    const float scl   = (z == 0) ? 0.125f : 1.0f;

    f32x4 acc[2][2];
    gemm_tile_body(A, xT, D_CH, m0, n0, l15, lhi, acc);

#pragma unroll
    for (int mf = 0; mf < 2; ++mf) {
#pragma unroll
        for (int r = 0; r < 4; ++r) {
            int m = m0 + mf * 16 + lhi * 4 + r;
            int head = m >> 6, dch = m & 63;
            float bi = bias[m];
#pragma unroll
            for (int nf = 0; nf < 2; ++nf) {
                int n = n0 + nf * 16 + l15;
                float v = (acc[mf][nf][r] + bi) * scl;
                size_t idx;
                if (z < 2)
                    idx = (size_t)head * HSTRIDE + (size_t)(n >> 4) * 1024 + (dch >> 5) * 512
                        + (((dch >> 3) & 3) * 16 + (n & 15)) * 8 + (dch & 7);
                else
                    idx = (size_t)head * HSTRIDE + (size_t)(n >> 6) * 4096 + (dch >> 4) * 1024
                        + ((n >> 5) & 1) * 512 + (((n >> 3) & 3) * 16 + (dch & 15)) * 8 + (n & 7);
                dst[idx] = (ushort_t)(cvt_pk(v, v) & 0xFFFF);
            }
        }
    }
}

// ---------------------------------------------------------------------------
// One 64-key attention tile. r19 reorder: V + next-S loads issued at tile
// top; S_lds store moved AFTER PV so PV no longer waits on the S vmcnt.
// Single-buffer safety: store still follows all of this tile's Sw reads
// (exp phase) and precedes next tile's reads in wave program order.
// ---------------------------------------------------------------------------
__device__ __forceinline__ void attn_tile(
    int kt, int ktn, const float* __restrict__ Sg,
    const ushort_t* __restrict__ Kh, const ushort_t* __restrict__ Vh,
    const bf16x8 (&qf)[2][2],
    ushort_t (* __restrict__ Sw)[72],
    f32x4 (&macc)[2][4], float (&lrun)[2],
    ushort_t (* __restrict__ Pw)[72], int l15, int lhi, int lane)
{
    // issue next tile's mask loads (8 instr, 4x256B segments each)
    f32x4 sr[8];
#pragma unroll
    for (int p = 0; p < 8; ++p)
        sr[p] = *(const f32x4*)&Sg[(size_t)p * 4 * NPTS + (size_t)ktn * 64];

    // issue V loads early (consumed at PV, far below)
    bf16x8 vf[8];
    const ushort_t* vb = Vh + (size_t)kt * 4096 + lane * 8;
#pragma unroll
    for (int mm = 0; mm < 2; ++mm)
#pragma unroll
        for (int db = 0; db < 4; ++db)
            vf[mm * 4 + db] = *(const bf16x8*)(vb + db * 1024 + mm * 512);

    // QK^T swapped for both q-frags: sacc[f][kb][r] = score[key][q=f*16+l15]
    f32x4 sacc0[4], sacc1[4];
    __builtin_amdgcn_s_setprio(1);
#pragma unroll
    for (int kb = 0; kb < 4; ++kb) {
        const ushort_t* kp = Kh + (size_t)(kt * 4 + kb) * 1024 + lane * 8;
        bf16x8 kf0 = *(const bf16x8*)kp;
        bf16x8 kf1 = *(const bf16x8*)(kp + 512);
        f32x4 z0 = (f32x4){0.f, 0.f, 0.f, 0.f};
        z0 = __builtin_amdgcn_mfma_f32_16x16x32_bf16(kf0, qf[0][0], z0, 0, 0, 0);
        z0 = __builtin_amdgcn_mfma_f32_16x16x32_bf16(kf1, qf[0][1], z0, 0, 0, 0);
        sacc0[kb] = z0;
        f32x4 z1 = (f32x4){0.f, 0.f, 0.f, 0.f};
        z1 = __builtin_amdgcn_mfma_f32_16x16x32_bf16(kf0, qf[1][0], z1, 0, 0, 0);
        z1 = __builtin_amdgcn_mfma_f32_16x16x32_bf16(kf1, qf[1][1], z1, 0, 0, 0);
        sacc1[kb] = z1;
    }
    __builtin_amdgcn_s_setprio(0);

    // p = exp(score * mask), both fragments; pack (HW cvt) -> P_lds
    float ts0 = 0.0f, ts1 = 0.0f;
#pragma unroll
    for (int kb = 0; kb < 4; ++kb) {
        unsigned a0 = *(const unsigned*)&Sw[l15][kb * 16 + lhi * 4];
        unsigned a1 = *(const unsigned*)&Sw[l15][kb * 16 + lhi * 4 + 2];
        unsigned b0 = *(const unsigned*)&Sw[16 + l15][kb * 16 + lhi * 4];
        unsigned b1 = *(const unsigned*)&Sw[16 + l15][kb * 16 + lhi * 4 + 2];
        float p00 = __expf(sacc0[kb][0] * bf2f((ushort_t)(a0 & 0xFFFF)));
        float p01 = __expf(sacc0[kb][1] * bf2f((ushort_t)(a0 >> 16)));
        float p02 = __expf(sacc0[kb][2] * bf2f((ushort_t)(a1 & 0xFFFF)));
        float p03 = __expf(sacc0[kb][3] * bf2f((ushort_t)(a1 >> 16)));
        float p10 = __expf(sacc1[kb][0] * bf2f((ushort_t)(b0 & 0xFFFF)));
        float p11 = __expf(sacc1[kb][1] * bf2f((ushort_t)(b0 >> 16)));
        float p12 = __expf(sacc1[kb][2] * bf2f((ushort_t)(b1 & 0xFFFF)));
        float p13 = __expf(sacc1[kb][3] * bf2f((ushort_t)(b1 >> 16)));
        ts0 += (p00 + p01) + (p02 + p03);
        ts1 += (p10 + p11) + (p12 + p13);
        *(unsigned*)&Pw[l15][kb * 16 + lhi * 4]          = cvt_pk(p00, p01);
        *(unsigned*)&Pw[l15][kb * 16 + lhi * 4 + 2]      = cvt_pk(p02, p03);
        *(unsigned*)&Pw[16 + l15][kb * 16 + lhi * 4]     = cvt_pk(p10, p11);
        *(unsigned*)&Pw[16 + l15][kb * 16 + lhi * 4 + 2] = cvt_pk(p12, p13);
    }
    lrun[0] += ts0;
    lrun[1] += ts1;

    // PV: mfma(A=V row=d, B=P col=q), both fragments share vf
    __builtin_amdgcn_s_setprio(1);
#pragma unroll
    for (int mm = 0; mm < 2; ++mm) {
        bf16x8 pf0 = *(const bf16x8*)&Pw[l15][mm * 32 + lhi * 8];
        bf16x8 pf1 = *(const bf16x8*)&Pw[16 + l15][mm * 32 + lhi * 8];
#pragma unroll
        for (int db = 0; db < 4; ++db) {
            macc[0][db] = __builtin_amdgcn_mfma_f32_16x16x32_bf16(vf[mm * 4 + db], pf0, macc[0][db], 0, 0, 0);
            macc[1][db] = __builtin_amdgcn_mfma_f32_16x16x32_bf16(vf[mm * 4 + db], pf1, macc[1][db], 0, 0, 0);
        }
    }
    __builtin_amdgcn_s_setprio(0);

    // store next tile's mask LAST (all Sw reads done; PV not gated on sr)
#pragma unroll
    for (int p = 0; p < 8; ++p) {
        *(unsigned*)&Sw[p * 4 + lhi][l15 * 4]     = cvt_pk(sr[p][0], sr[p][1]);
        *(unsigned*)&Sw[p * 4 + lhi][l15 * 4 + 2] = cvt_pk(sr[p][2], sr[p][3]);
    }
}

// ---------------------------------------------------------------------------
// MFMA flash attention: 32 q/warp, per-head blocks, key-split 8.
// Grid (32, NHEAD, KSPLIT); block 256.
// ---------------------------------------------------------------------------
__global__ __launch_bounds__(256, 3) void attn_mfma(
    const ushort_t* __restrict__ Qf, const ushort_t* __restrict__ Kf,
    const ushort_t* __restrict__ Vf, const float* __restrict__ S,
    ushort_t* __restrict__ pacc, float* __restrict__ pl)
{
    __shared__ __align__(16) ushort_t P_lds[4][32][72];   // 18432 B
    __shared__ __align__(16) ushort_t S_lds[4][32][72];   // 18432 B

    const int tid  = threadIdx.x;
    const int w    = tid >> 6;
    const int lane = tid & 63;
    const int l15  = lane & 15;
    const int lhi  = lane >> 4;
    const int h    = blockIdx.y;
    const int ks   = blockIdx.z;
    const int q0   = blockIdx.x * 128 + w * 32;
    const int ktb  = ks * (KCHUNK / 64);

    const ushort_t* Kh = Kf + (size_t)h * HSTRIDE;
    const ushort_t* Vh = Vf + (size_t)h * HSTRIDE;
    const float* Sg = S + (size_t)(q0 + lhi) * NPTS + l15 * 4;
    ushort_t (* __restrict__ Pw)[72] = P_lds[w];
    ushort_t (* __restrict__ Sw)[72] = S_lds[w];

    bf16x8 qf[2][2];
#pragma unroll
    for (int f = 0; f < 2; ++f) {
        const ushort_t* qp = Qf + (size_t)h * HSTRIDE
                           + (size_t)((q0 + f * 16) >> 4) * 1024 + lane * 8;
        qf[f][0] = *(const bf16x8*)qp;
        qf[f][1] = *(const bf16x8*)(qp + 512);
    }

    f32x4 macc[2][4];
#pragma unroll
    for (int f = 0; f < 2; ++f)
#pragma unroll
        for (int db = 0; db < 4; ++db) macc[f][db] = (f32x4){0.f, 0.f, 0.f, 0.f};
    float lrun[2] = {0.0f, 0.0f};

    // prologue: stage mask tile ktb
    {
#pragma unroll
        for (int p = 0; p < 8; ++p) {
            f32x4 t = *(const f32x4*)&Sg[(size_t)p * 4 * NPTS + (size_t)ktb * 64];
            *(unsigned*)&Sw[p * 4 + lhi][l15 * 4]     = cvt_pk(t[0], t[1]);
            *(unsigned*)&Sw[p * 4 + lhi][l15 * 4 + 2] = cvt_pk(t[2], t[3]);
        }
    }

    // 8 tiles; prefetch distance 1 (wrap on last is harmless)
    for (int kt = ktb; kt < ktb + 8; ++kt) {
        const int ktn = (kt + 1 < ktb + 8) ? kt + 1 : ktb;
        attn_tile(kt, ktn, Sg, Kh, Vh, qf, Sw, macc, lrun, Pw, l15, lhi, lane);
    }

    // deferred cross-group l reduction (once per block)
#pragma unroll
    for (int f = 0; f < 2; ++f) {
        lrun[f] += __shfl_xor(lrun[f], 16);
        lrun[f] += __shfl_xor(lrun[f], 32);
    }

    // store unnormalized partials for both fragments
    const size_t pb = ((size_t)ks * NHEAD + h) * NPTS;
#pragma unroll
    for (int f = 0; f < 2; ++f) {
        ushort_t* prow = pacc + (pb + q0 + f * 16 + l15) * DHEAD;
#pragma unroll
        for (int db = 0; db < 4; ++db) {
            *(unsigned*)&prow[db * 16 + lhi * 4]     = cvt_pk(macc[f][db][0], macc[f][db][1]);
            *(unsigned*)&prow[db * 16 + lhi * 4 + 2] = cvt_pk(macc[f][db][2], macc[f][db][3]);
        }
    }
    if (lane < 16) {
        pl[pb + q0 + lane]      = lrun[0];
        pl[pb + q0 + 16 + lane] = lrun[1];
    }
}

// ---------------------------------------------------------------------------
// FUSED MERGE + MLP on 16-point blocks (grid 256 = 1 block/CU).
// Phase A: merge KSPLIT partials -> msgT (element formulas = proven merge;
// threads 0-127 handle heads 0-1, threads 128-255 heads 2-3).
// Phases B/C/D: warp-tile 32m x 16n MFMA chain via block-local global
// scratch RAW across __syncthreads (mechanism proven in r17/r18).
// ---------------------------------------------------------------------------
__global__ __launch_bounds__(256) void mlp_fused(
    const ushort_t* __restrict__ pacc, const float* __restrict__ pl,
    ushort_t* __restrict__ msgT,
    const float* __restrict__ W1, const float* __restrict__ b1,
    const float* __restrict__ g1, const float* __restrict__ be1,
    const float* __restrict__ W2, const float* __restrict__ b2,
    const float* __restrict__ g2, const float* __restrict__ be2,
    const float* __restrict__ W3, const float* __restrict__ b3,
    const float* __restrict__ x, float* __restrict__ out,
    ushort_t* __restrict__ h1T, ushort_t* __restrict__ h2T)
{
    const int tid = threadIdx.x;
    const int w = tid >> 6, lane = tid & 63, l15 = lane & 15, lhi = lane >> 4;
    const int nblk = blockIdx.x * 16;

    // --- Phase A: merge partials -> msgT (16 rows; 2 heads per thread-half)
    {
        const int hb  = (tid >> 7) * 2;       // 0 or 2
        const int loc = tid & 127;
        const int ql  = loc >> 3;             // 0..15
        const int d0  = (loc & 7) * 8;        // 0..56
#pragma unroll
        for (int hh = 0; hh < 2; ++hh) {
            const int h = hb + hh;
            float ls = 0.0f;
#pragma unroll
            for (int ks = 0; ks < KSPLIT; ++ks)
                ls += pl[((size_t)ks * NHEAD + h) * NPTS + nblk + ql];
            float inv = 1.0f / ls;
            float o[8];
#pragma unroll
            for (int j = 0; j < 8; ++j) o[j] = 0.0f;
#pragma unroll
            for (int ks = 0; ks < KSPLIT; ++ks) {
                const ushort_t* ap = pacc
                    + (((size_t)ks * NHEAD + h) * NPTS + nblk + ql) * DHEAD + d0;
                bf16x8 v = *(const bf16x8*)ap;
#pragma unroll
                for (int j = 0; j < 8; ++j) o[j] += bf2f((ushort_t)v[j]);
            }
            unsigned* dp = (unsigned*)(msgT + (size_t)(nblk + ql) * D_CH + h * 64 + d0);
            dp[0] = cvt_pk(o[0] * inv, o[1] * inv);
            dp[1] = cvt_pk(o[2] * inv, o[3] * inv);
            dp[2] = cvt_pk(o[4] * inv, o[5] * inv);
            dp[3] = cvt_pk(o[6] * inv, o[7] * inv);
        }
    }
    __syncthreads();

    // --- Phase B: h1 = relu(bn1(W1 . msg)), M=128 K=256, n=16 --------------
    {
        f32x4 acc[2];
        acc[0] = (f32x4){0.f, 0.f, 0.f, 0.f};
        acc[1] = (f32x4){0.f, 0.f, 0.f, 0.f};
        const ushort_t* Bt = msgT + (size_t)nblk * D_CH;
        for (int k0 = 0; k0 < 256; k0 += 32) {
            bf16x8 bfr = *(const bf16x8*)&Bt[(size_t)l15 * D_CH + k0 + lhi * 8];
#pragma unroll
            for (int mf = 0; mf < 2; ++mf) {
                const float* ap = W1 + (size_t)(w * 32 + mf * 16 + l15) * 256 + k0 + lhi * 8;
                float4 a0 = *(const float4*)ap;
                float4 a1 = *(const float4*)(ap + 4);
                bf16x8 af;
                unsigned* tp = (unsigned*)&af;
                tp[0] = cvt_pk(a0.x, a0.y); tp[1] = cvt_pk(a0.z, a0.w);
                tp[2] = cvt_pk(a1.x, a1.y); tp[3] = cvt_pk(a1.z, a1.w);
                acc[mf] = __builtin_amdgcn_mfma_f32_16x16x32_bf16(af, bfr, acc[mf], 0, 0, 0);
            }
        }
#pragma unroll
        for (int mf = 0; mf < 2; ++mf)
#pragma unroll
            for (int r = 0; r < 4; ++r) {
                int m = w * 32 + mf * 16 + lhi * 4 + r;
                float bi = b1[m], sc = g1[m] * BN_RSQ, sh = be1[m];
                float v = fmaxf((acc[mf][r] + bi) * sc + sh, 0.0f);
                h1T[(size_t)(nblk + l15) * 128 + m] = (ushort_t)(cvt_pk(v, v) & 0xFFFF);
            }
    }
    __syncthreads();

    // --- Phase C: h2 = relu(bn2(W2 . h1)), M=128 K=128, n=16 ----------------
    {
        f32x4 acc[2];
        acc[0] = (f32x4){0.f, 0.f, 0.f, 0.f};
        acc[1] = (f32x4){0.f, 0.f, 0.f, 0.f};
        const ushort_t* Bt = h1T + (size_t)nblk * 128;
        for (int k0 = 0; k0 < 128; k0 += 32) {
            bf16x8 bfr = *(const bf16x8*)&Bt[(size_t)l15 * 128 + k0 + lhi * 8];
#pragma unroll
            for (int mf = 0; mf < 2; ++mf) {
                const float* ap = W2 + (size_t)(w * 32 + mf * 16 + l15) * 128 + k0 + lhi * 8;
                float4 a0 = *(const float4*)ap;
                float4 a1 = *(const float4*)(ap + 4);
                bf16x8 af;
                unsigned* tp = (unsigned*)&af;
                tp[0] = cvt_pk(a0.x, a0.y); tp[1] = cvt_pk(a0.z, a0.w);
                tp[2] = cvt_pk(a1.x, a1.y); tp[3] = cvt_pk(a1.z, a1.w);
                acc[mf] = __builtin_amdgcn_mfma_f32_16x16x32_bf16(af, bfr, acc[mf], 0, 0, 0);
            }
        }
#pragma unroll
        for (int mf = 0; mf < 2; ++mf)
#pragma unroll
            for (int r = 0; r < 4; ++r) {
                int m = w * 32 + mf * 16 + lhi * 4 + r;
                float bi = b2[m], sc = g2[m] * BN_RSQ, sh = be2[m];
                float v = fmaxf((acc[mf][r] + bi) * sc + sh, 0.0f);
                h2T[(size_t)(nblk + l15) * 128 + m] = (ushort_t)(cvt_pk(v, v) & 0xFFFF);
            }
    }
    __syncthreads();

    // --- Phase D: out = x + W3 . h2, M=256 K=128, n=16 ----------------------
    {
        f32x4 acc[4];
#pragma unroll
        for (int i = 0; i < 4; ++i) acc[i] = (f32x4){0.f, 0.f, 0.f, 0.f};
        const ushort_t* Bt = h2T + (size_t)nblk * 128;
        for (int k0 = 0; k0 < 128; k0 += 32) {
            bf16x8 bfr = *(const bf16x8*)&Bt[(size_t)l15 * 128 + k0 + lhi * 8];
#pragma unroll
            for (int mf = 0; mf < 4; ++mf) {
                const float* ap = W3 + (size_t)(w * 64 + mf * 16 + l15) * 128 + k0 + lhi * 8;
                float4 a0 = *(const float4*)ap;
                float4 a1 = *(const float4*)(ap + 4);
                bf16x8 af;
                unsigned* tp = (unsigned*)&af;
                tp[0] = cvt_pk(a0.x, a0.y); tp[1] = cvt_pk(a0.z, a0.w);
                tp[2] = cvt_pk(a1.x, a1.y); tp[3] = cvt_pk(a1.z, a1.w);
                acc[mf] = __builtin_amdgcn_mfma_f32_16x16x32_bf16(af, bfr, acc[mf], 0, 0, 0);
            }
        }
#pragma unroll
        for (int mf = 0; mf < 4; ++mf)
#pragma unroll
            for (int r = 0; r < 4; ++r) {
                int m = w * 64 + mf * 16 + lhi * 4 + r;
                float bi = b3[m];
                int n = nblk + l15;
                out[(size_t)m * NPTS + n] = acc[mf][r] + bi + x[(size_t)m * NPTS + n];
            }
    }
}

// ---------------------------------------------------------------------------
extern "C" void kernel_launch(void* const* d_in, const int* in_sizes, int n_in,
                              void* d_out, int out_size, void* d_ws, size_t ws_size,
                              hipStream_t stream) {
    const float* x  = (const float*)d_in[0];
    const float* S  = (const float*)d_in[1];
    const float* Wq = (const float*)d_in[2];
    const float* bq = (const float*)d_in[3];
    const float* Wk = (const float*)d_in[4];
    const float* bk = (const float*)d_in[5];
    const float* Wv = (const float*)d_in[6];
    const float* bv = (const float*)d_in[7];
    const float* W1 = (const float*)d_in[8];
    const float* b1 = (const float*)d_in[9];
    const float* g1 = (const float*)d_in[10];
    const float* be1= (const float*)d_in[11];
    const float* W2 = (const float*)d_in[12];
    const float* b2 = (const float*)d_in[13];
    const float* g2 = (const float*)d_in[14];
    const float* be2= (const float*)d_in[15];
    const float* W3 = (const float*)d_in[16];
    const float* b3 = (const float*)d_in[17];

    char* ws = (char*)d_ws;
    const size_t MB = 1024 * 1024;
    ushort_t* xT   = (ushort_t*)(ws);                        // 2 MB
    ushort_t* Qf   = (ushort_t*)(ws + 2 * MB);               // 2 MB
    ushort_t* Kf   = (ushort_t*)(ws + 4 * MB);               // 2 MB
    ushort_t* Vf   = (ushort_t*)(ws + 6 * MB);               // 2 MB
    ushort_t* pacc = (ushort_t*)(ws + 8 * MB);               // 16 MB
    float*    pl   = (float*)   (ws + 24 * MB);              // 512 KB
    ushort_t* msgT = (ushort_t*)(ws + 25 * MB);              // 2 MB
    ushort_t* h1T  = (ushort_t*)(ws + 27 * MB);              // 1 MB
    ushort_t* h2T  = (ushort_t*)(ws + 28 * MB);              // 1 MB

    transpose_cast<<<dim3(64, 4), 256, 0, stream>>>(x, xT);
    gemm_qkv<<<dim3(64, 4, 3), 256, 0, stream>>>(Wq, bq, Wk, bk, Wv, bv, xT, Qf, Kf, Vf);

    attn_mfma<<<dim3(32, NHEAD, KSPLIT), 256, 0, stream>>>(Qf, Kf, Vf, S, pacc, pl);

    mlp_fused<<<dim3(256), 256, 0, stream>>>(pacc, pl, msgT,
        W1, b1, g1, be1, W2, b2, g2, be2, W3, b3, x, (float*)d_out, h1T, h2T);
}

// Round 20
// 85.682 us; speedup vs baseline: 1.4683x; 1.1413x over previous
//
#include <hip/hip_runtime.h>
#include <hip/hip_bf16.h>
#include <math.h>

#define D_CH   256
#define NHEAD  4
#define DHEAD  64
#define NPTS   4096
#define KSPLIT 8
#define KCHUNK (NPTS / KSPLIT)          // 512 keys = 8 tiles of 64
#define BN_RSQ 0.99999500003749963f     // 1/sqrt(1 + 1e-5)
#define HSTRIDE 262144                  // 4096*64 ushorts per head

typedef __attribute__((ext_vector_type(4))) float f32x4;
typedef __attribute__((ext_vector_type(8))) short bf16x8;
typedef unsigned short ushort_t;

__device__ __forceinline__ ushort_t f2bf(float x) {
    unsigned int b = __float_as_uint(x);
    return (ushort_t)((b + 0x7FFF + ((b >> 16) & 1)) >> 16);  // RNE (scalar fallback)
}
__device__ __forceinline__ float bf2f(ushort_t u) {
    return __uint_as_float(((unsigned int)u) << 16);
}
// HW packed f32x2 -> bf16x2 (RNE), single VALU op (T12 primitive, m240)
__device__ __forceinline__ unsigned cvt_pk(float lo, float hi) {
    unsigned r;
    asm("v_cvt_pk_bf16_f32 %0, %1, %2" : "=v"(r) : "v"(lo), "v"(hi));
    return r;
}

// ---------------------------------------------------------------------------
// Fused QKV projection with IN-KERNEL x transpose (replaces transpose_cast):
// stage x[0:256][nb:nb+64] -> Bs[n][k] bf16 in LDS (transpose_cast pattern,
// pad 266 so writes are 2-way and ds_read_b128 is conflict-clean), then the
// MFMA k-loop reads B-fragments from LDS. 0.125 folded into Q.
// ---------------------------------------------------------------------------
__global__ __launch_bounds__(256) void gemm_qkv(
    const float* __restrict__ Wq, const float* __restrict__ bq,
    const float* __restrict__ Wk, const float* __restrict__ bk,
    const float* __restrict__ Wv, const float* __restrict__ bv,
    const float* __restrict__ x,
    ushort_t* __restrict__ Qf, ushort_t* __restrict__ Kf, ushort_t* __restrict__ Vf)
{
    __shared__ __align__(16) ushort_t Bs[64][266];   // [n][k] bf16, 34048 B

    const int tid = threadIdx.x;
    const int w = tid >> 6, lane = tid & 63, l15 = lane & 15, lhi = lane >> 4;
    const int wm = w >> 1, wn = w & 1;
    const int m0 = blockIdx.y * 64 + wm * 32;
    const int nb = blockIdx.x * 64;
    const int z = blockIdx.z;

    // stage: coalesced f32 row reads -> bf16 transpose-store
#pragma unroll
    for (int kc = 0; kc < 256; kc += 64) {
#pragma unroll
        for (int p = 0; p < 16; ++p) {
            int idx = p * 256 + tid;
            int kk = idx >> 6, nn = idx & 63;
            Bs[nn][kc + kk] = f2bf(x[(size_t)(kc + kk) * NPTS + nb + nn]);
        }
    }
    __syncthreads();

    const float* A    = (z == 0) ? Wq : (z == 1) ? Wk : Wv;
    const float* bias = (z == 0) ? bq : (z == 1) ? bk : bv;
    ushort_t* dst     = (z == 0) ? Qf : (z == 1) ? Kf : Vf;
    const float scl   = (z == 0) ? 0.125f : 1.0f;

    f32x4 acc[2][2];
#pragma unroll
    for (int i = 0; i < 2; ++i)
#pragma unroll
        for (int j = 0; j < 2; ++j) acc[i][j] = (f32x4){0.f, 0.f, 0.f, 0.f};

    for (int k0 = 0; k0 < D_CH; k0 += 32) {
        bf16x8 af[2], bfr[2];
#pragma unroll
        for (int mf = 0; mf < 2; ++mf) {
            const float* ap = A + (size_t)(m0 + mf * 16 + l15) * D_CH + k0 + lhi * 8;
            float4 a0 = *(const float4*)ap;
            float4 a1 = *(const float4*)(ap + 4);
            unsigned* tp = (unsigned*)&af[mf];
            tp[0] = cvt_pk(a0.x, a0.y);
            tp[1] = cvt_pk(a0.z, a0.w);
            tp[2] = cvt_pk(a1.x, a1.y);
            tp[3] = cvt_pk(a1.z, a1.w);
        }
#pragma unroll
        for (int nf = 0; nf < 2; ++nf)
            bfr[nf] = *(const bf16x8*)&Bs[wn * 32 + nf * 16 + l15][k0 + lhi * 8];
#pragma unroll
        for (int mf = 0; mf < 2; ++mf)
#pragma unroll
            for (int nf = 0; nf < 2; ++nf)
                acc[mf][nf] = __builtin_amdgcn_mfma_f32_16x16x32_bf16(af[mf], bfr[nf], acc[mf][nf], 0, 0, 0);
    }

#pragma unroll
    for (int mf = 0; mf < 2; ++mf) {
#pragma unroll
        for (int r = 0; r < 4; ++r) {
            int m = m0 + mf * 16 + lhi * 4 + r;
            int head = m >> 6, dch = m & 63;
            float bi = bias[m];
#pragma unroll
            for (int nf = 0; nf < 2; ++nf) {
                int n = nb + wn * 32 + nf * 16 + l15;
                float v = (acc[mf][nf][r] + bi) * scl;
                size_t idx;
                if (z < 2)
                    idx = (size_t)head * HSTRIDE + (size_t)(n >> 4) * 1024 + (dch >> 5) * 512
                        + (((dch >> 3) & 3) * 16 + (n & 15)) * 8 + (dch & 7);
                else
                    idx = (size_t)head * HSTRIDE + (size_t)(n >> 6) * 4096 + (dch >> 4) * 1024
                        + ((n >> 5) & 1) * 512 + (((n >> 3) & 3) * 16 + (dch & 15)) * 8 + (n & 7);
                dst[idx] = (ushort_t)(cvt_pk(v, v) & 0xFFFF);
            }
        }
    }
}

// ---------------------------------------------------------------------------
// One 64-key attention tile (r18 ordering — measured best).
// ---------------------------------------------------------------------------
__device__ __forceinline__ void attn_tile(
    int kt, int ktn, const float* __restrict__ Sg,
    const ushort_t* __restrict__ Kh, const ushort_t* __restrict__ Vh,
    const bf16x8 (&qf)[2][2],
    ushort_t (* __restrict__ Sw)[72],
    f32x4 (&macc)[2][4], float (&lrun)[2],
    ushort_t (* __restrict__ Pw)[72], int l15, int lhi, int lane)
{
    // issue next tile's mask loads (8 instr, 4x256B segments each)
    f32x4 sr[8];
#pragma unroll
    for (int p = 0; p < 8; ++p)
        sr[p] = *(const f32x4*)&Sg[(size_t)p * 4 * NPTS + (size_t)ktn * 64];

    // QK^T swapped for both q-frags: sacc[f][kb][r] = score[key][q=f*16+l15]
    f32x4 sacc0[4], sacc1[4];
    __builtin_amdgcn_s_setprio(1);
#pragma unroll
    for (int kb = 0; kb < 4; ++kb) {
        const ushort_t* kp = Kh + (size_t)(kt * 4 + kb) * 1024 + lane * 8;
        bf16x8 kf0 = *(const bf16x8*)kp;
        bf16x8 kf1 = *(const bf16x8*)(kp + 512);
        f32x4 z0 = (f32x4){0.f, 0.f, 0.f, 0.f};
        z0 = __builtin_amdgcn_mfma_f32_16x16x32_bf16(kf0, qf[0][0], z0, 0, 0, 0);
        z0 = __builtin_amdgcn_mfma_f32_16x16x32_bf16(kf1, qf[0][1], z0, 0, 0, 0);
        sacc0[kb] = z0;
        f32x4 z1 = (f32x4){0.f, 0.f, 0.f, 0.f};
        z1 = __builtin_amdgcn_mfma_f32_16x16x32_bf16(kf0, qf[1][0], z1, 0, 0, 0);
        z1 = __builtin_amdgcn_mfma_f32_16x16x32_bf16(kf1, qf[1][1], z1, 0, 0, 0);
        sacc1[kb] = z1;
    }
    __builtin_amdgcn_s_setprio(0);

    // issue V loads (shared by both fragments)
    bf16x8 vf[8];
    const ushort_t* vb = Vh + (size_t)kt * 4096 + lane * 8;
#pragma unroll
    for (int mm = 0; mm < 2; ++mm)
#pragma unroll
        for (int db = 0; db < 4; ++db)
            vf[mm * 4 + db] = *(const bf16x8*)(vb + db * 1024 + mm * 512);

    // p = exp(score * mask), both fragments; pack (HW cvt) -> P_lds
    float ts0 = 0.0f, ts1 = 0.0f;
#pragma unroll
    for (int kb = 0; kb < 4; ++kb) {
        unsigned a0 = *(const unsigned*)&Sw[l15][kb * 16 + lhi * 4];
        unsigned a1 = *(const unsigned*)&Sw[l15][kb * 16 + lhi * 4 + 2];
        unsigned b0 = *(const unsigned*)&Sw[16 + l15][kb * 16 + lhi * 4];
        unsigned b1 = *(const unsigned*)&Sw[16 + l15][kb * 16 + lhi * 4 + 2];
        float p00 = __expf(sacc0[kb][0] * bf2f((ushort_t)(a0 & 0xFFFF)));
        float p01 = __expf(sacc0[kb][1] * bf2f((ushort_t)(a0 >> 16)));
        float p02 = __expf(sacc0[kb][2] * bf2f((ushort_t)(a1 & 0xFFFF)));
        float p03 = __expf(sacc0[kb][3] * bf2f((ushort_t)(a1 >> 16)));
        float p10 = __expf(sacc1[kb][0] * bf2f((ushort_t)(b0 & 0xFFFF)));
        float p11 = __expf(sacc1[kb][1] * bf2f((ushort_t)(b0 >> 16)));
        float p12 = __expf(sacc1[kb][2] * bf2f((ushort_t)(b1 & 0xFFFF)));
        float p13 = __expf(sacc1[kb][3] * bf2f((ushort_t)(b1 >> 16)));
        ts0 += (p00 + p01) + (p02 + p03);
        ts1 += (p10 + p11) + (p12 + p13);
        *(unsigned*)&Pw[l15][kb * 16 + lhi * 4]          = cvt_pk(p00, p01);
        *(unsigned*)&Pw[l15][kb * 16 + lhi * 4 + 2]      = cvt_pk(p02, p03);
        *(unsigned*)&Pw[16 + l15][kb * 16 + lhi * 4]     = cvt_pk(p10, p11);
        *(unsigned*)&Pw[16 + l15][kb * 16 + lhi * 4 + 2] = cvt_pk(p12, p13);
    }
    lrun[0] += ts0;
    lrun[1] += ts1;

    // store next tile's mask (all Sw reads done; sr regs die here)
#pragma unroll
    for (int p = 0; p < 8; ++p) {
        *(unsigned*)&Sw[p * 4 + lhi][l15 * 4]     = cvt_pk(sr[p][0], sr[p][1]);
        *(unsigned*)&Sw[p * 4 + lhi][l15 * 4 + 2] = cvt_pk(sr[p][2], sr[p][3]);
    }

    // PV: mfma(A=V row=d, B=P col=q), both fragments share vf
    __builtin_amdgcn_s_setprio(1);
#pragma unroll
    for (int mm = 0; mm < 2; ++mm) {
        bf16x8 pf0 = *(const bf16x8*)&Pw[l15][mm * 32 + lhi * 8];
        bf16x8 pf1 = *(const bf16x8*)&Pw[16 + l15][mm * 32 + lhi * 8];
#pragma unroll
        for (int db = 0; db < 4; ++db) {
            macc[0][db] = __builtin_amdgcn_mfma_f32_16x16x32_bf16(vf[mm * 4 + db], pf0, macc[0][db], 0, 0, 0);
            macc[1][db] = __builtin_amdgcn_mfma_f32_16x16x32_bf16(vf[mm * 4 + db], pf1, macc[1][db], 0, 0, 0);
        }
    }
    __builtin_amdgcn_s_setprio(0);
}

// ---------------------------------------------------------------------------
// MFMA flash attention (r18 form): 32 q/warp, per-head blocks, key-split 8.
// Grid (32, NHEAD, KSPLIT); block 256.
// ---------------------------------------------------------------------------
__global__ __launch_bounds__(256, 3) void attn_mfma(
    const ushort_t* __restrict__ Qf, const ushort_t* __restrict__ Kf,
    const ushort_t* __restrict__ Vf, const float* __restrict__ S,
    ushort_t* __restrict__ pacc, float* __restrict__ pl)
{
    __shared__ __align__(16) ushort_t P_lds[4][32][72];   // 18432 B
    __shared__ __align__(16) ushort_t S_lds[4][32][72];   // 18432 B

    const int tid  = threadIdx.x;
    const int w    = tid >> 6;
    const int lane = tid & 63;
    const int l15  = lane & 15;
    const int lhi  = lane >> 4;
    const int h    = blockIdx.y;
    const int ks   = blockIdx.z;
    const int q0   = blockIdx.x * 128 + w * 32;
    const int ktb  = ks * (KCHUNK / 64);

    const ushort_t* Kh = Kf + (size_t)h * HSTRIDE;
    const ushort_t* Vh = Vf + (size_t)h * HSTRIDE;
    const float* Sg = S + (size_t)(q0 + lhi) * NPTS + l15 * 4;
    ushort_t (* __restrict__ Pw)[72] = P_lds[w];
    ushort_t (* __restrict__ Sw)[72] = S_lds[w];

    bf16x8 qf[2][2];
#pragma unroll
    for (int f = 0; f < 2; ++f) {
        const ushort_t* qp = Qf + (size_t)h * HSTRIDE
                           + (size_t)((q0 + f * 16) >> 4) * 1024 + lane * 8;
        qf[f][0] = *(const bf16x8*)qp;
        qf[f][1] = *(const bf16x8*)(qp + 512);
    }

    f32x4 macc[2][4];
#pragma unroll
    for (int f = 0; f < 2; ++f)
#pragma unroll
        for (int db = 0; db < 4; ++db) macc[f][db] = (f32x4){0.f, 0.f, 0.f, 0.f};
    float lrun[2] = {0.0f, 0.0f};

    // prologue: stage mask tile ktb
    {
#pragma unroll
        for (int p = 0; p < 8; ++p) {
            f32x4 t = *(const f32x4*)&Sg[(size_t)p * 4 * NPTS + (size_t)ktb * 64];
            *(unsigned*)&Sw[p * 4 + lhi][l15 * 4]     = cvt_pk(t[0], t[1]);
            *(unsigned*)&Sw[p * 4 + lhi][l15 * 4 + 2] = cvt_pk(t[2], t[3]);
        }
    }

    // 8 tiles; prefetch distance 1 (wrap on last is harmless)
    for (int kt = ktb; kt < ktb + 8; ++kt) {
        const int ktn = (kt + 1 < ktb + 8) ? kt + 1 : ktb;
        attn_tile(kt, ktn, Sg, Kh, Vh, qf, Sw, macc, lrun, Pw, l15, lhi, lane);
    }

    // deferred cross-group l reduction (once per block)
#pragma unroll
    for (int f = 0; f < 2; ++f) {
        lrun[f] += __shfl_xor(lrun[f], 16);
        lrun[f] += __shfl_xor(lrun[f], 32);
    }

    // store unnormalized partials for both fragments
    const size_t pb = ((size_t)ks * NHEAD + h) * NPTS;
#pragma unroll
    for (int f = 0; f < 2; ++f) {
        ushort_t* prow = pacc + (pb + q0 + f * 16 + l15) * DHEAD;
#pragma unroll
        for (int db = 0; db < 4; ++db) {
            *(unsigned*)&prow[db * 16 + lhi * 4]     = cvt_pk(macc[f][db][0], macc[f][db][1]);
            *(unsigned*)&prow[db * 16 + lhi * 4 + 2] = cvt_pk(macc[f][db][2], macc[f][db][3]);
        }
    }
    if (lane < 16) {
        pl[pb + q0 + lane]      = lrun[0];
        pl[pb + q0 + 16 + lane] = lrun[1];
    }
}

// ---------------------------------------------------------------------------
// FUSED MERGE + MLP on 16-point blocks (r19 form, proven).
// ---------------------------------------------------------------------------
__global__ __launch_bounds__(256) void mlp_fused(
    const ushort_t* __restrict__ pacc, const float* __restrict__ pl,
    ushort_t* __restrict__ msgT,
    const float* __restrict__ W1, const float* __restrict__ b1,
    const float* __restrict__ g1, const float* __restrict__ be1,
    const float* __restrict__ W2, const float* __restrict__ b2,
    const float* __restrict__ g2, const float* __restrict__ be2,
    const float* __restrict__ W3, const float* __restrict__ b3,
    const float* __restrict__ x, float* __restrict__ out,
    ushort_t* __restrict__ h1T, ushort_t* __restrict__ h2T)
{
    const int tid = threadIdx.x;
    const int w = tid >> 6, lane = tid & 63, l15 = lane & 15, lhi = lane >> 4;
    const int nblk = blockIdx.x * 16;

    // --- Phase A: merge partials -> msgT (16 rows; 2 heads per thread-half)
    {
        const int hb  = (tid >> 7) * 2;       // 0 or 2
        const int loc = tid & 127;
        const int ql  = loc >> 3;             // 0..15
        const int d0  = (loc & 7) * 8;        // 0..56
#pragma unroll
        for (int hh = 0; hh < 2; ++hh) {
            const int h = hb + hh;
            float ls = 0.0f;
#pragma unroll
            for (int ks = 0; ks < KSPLIT; ++ks)
                ls += pl[((size_t)ks * NHEAD + h) * NPTS + nblk + ql];
            float inv = 1.0f / ls;
            float o[8];
#pragma unroll
            for (int j = 0; j < 8; ++j) o[j] = 0.0f;
#pragma unroll
            for (int ks = 0; ks < KSPLIT; ++ks) {
                const ushort_t* ap = pacc
                    + (((size_t)ks * NHEAD + h) * NPTS + nblk + ql) * DHEAD + d0;
                bf16x8 v = *(const bf16x8*)ap;
#pragma unroll
                for (int j = 0; j < 8; ++j) o[j] += bf2f((ushort_t)v[j]);
            }
            unsigned* dp = (unsigned*)(msgT + (size_t)(nblk + ql) * D_CH + h * 64 + d0);
            dp[0] = cvt_pk(o[0] * inv, o[1] * inv);
            dp[1] = cvt_pk(o[2] * inv, o[3] * inv);
            dp[2] = cvt_pk(o[4] * inv, o[5] * inv);
            dp[3] = cvt_pk(o[6] * inv, o[7] * inv);
        }
    }
    __syncthreads();

    // --- Phase B: h1 = relu(bn1(W1 . msg)), M=128 K=256, n=16 --------------
    {
        f32x4 acc[2];
        acc[0] = (f32x4){0.f, 0.f, 0.f, 0.f};
        acc[1] = (f32x4){0.f, 0.f, 0.f, 0.f};
        const ushort_t* Bt = msgT + (size_t)nblk * D_CH;
        for (int k0 = 0; k0 < 256; k0 += 32) {
            bf16x8 bfr = *(const bf16x8*)&Bt[(size_t)l15 * D_CH + k0 + lhi * 8];
#pragma unroll
            for (int mf = 0; mf < 2; ++mf) {
                const float* ap = W1 + (size_t)(w * 32 + mf * 16 + l15) * 256 + k0 + lhi * 8;
                float4 a0 = *(const float4*)ap;
                float4 a1 = *(const float4*)(ap + 4);
                bf16x8 af;
                unsigned* tp = (unsigned*)&af;
                tp[0] = cvt_pk(a0.x, a0.y); tp[1] = cvt_pk(a0.z, a0.w);
                tp[2] = cvt_pk(a1.x, a1.y); tp[3] = cvt_pk(a1.z, a1.w);
                acc[mf] = __builtin_amdgcn_mfma_f32_16x16x32_bf16(af, bfr, acc[mf], 0, 0, 0);
            }
        }
#pragma unroll
        for (int mf = 0; mf < 2; ++mf)
#pragma unroll
            for (int r = 0; r < 4; ++r) {
                int m = w * 32 + mf * 16 + lhi * 4 + r;
                float bi = b1[m], sc = g1[m] * BN_RSQ, sh = be1[m];
                float v = fmaxf((acc[mf][r] + bi) * sc + sh, 0.0f);
                h1T[(size_t)(nblk + l15) * 128 + m] = (ushort_t)(cvt_pk(v, v) & 0xFFFF);
            }
    }
    __syncthreads();

    // --- Phase C: h2 = relu(bn2(W2 . h1)), M=128 K=128, n=16 ----------------
    {
        f32x4 acc[2];
        acc[0] = (f32x4){0.f, 0.f, 0.f, 0.f};
        acc[1] = (f32x4){0.f, 0.f, 0.f, 0.f};
        const ushort_t* Bt = h1T + (size_t)nblk * 128;
        for (int k0 = 0; k0 < 128; k0 += 32) {
            bf16x8 bfr = *(const bf16x8*)&Bt[(size_t)l15 * 128 + k0 + lhi * 8];
#pragma unroll
            for (int mf = 0; mf < 2; ++mf) {
                const float* ap = W2 + (size_t)(w * 32 + mf * 16 + l15) * 128 + k0 + lhi * 8;
                float4 a0 = *(const float4*)ap;
                float4 a1 = *(const float4*)(ap + 4);
                bf16x8 af;
                unsigned* tp = (unsigned*)&af;
                tp[0] = cvt_pk(a0.x, a0.y); tp[1] = cvt_pk(a0.z, a0.w);
                tp[2] = cvt_pk(a1.x, a1.y); tp[3] = cvt_pk(a1.z, a1.w);
                acc[mf] = __builtin_amdgcn_mfma_f32_16x16x32_bf16(af, bfr, acc[mf], 0, 0, 0);
            }
        }
#pragma unroll
        for (int mf = 0; mf < 2; ++mf)
#pragma unroll
            for (int r = 0; r < 4; ++r) {
                int m = w * 32 + mf * 16 + lhi * 4 + r;
                float bi = b2[m], sc = g2[m] * BN_RSQ, sh = be2[m];
                float v = fmaxf((acc[mf][r] + bi) * sc + sh, 0.0f);
                h2T[(size_t)(nblk + l15) * 128 + m] = (ushort_t)(cvt_pk(v, v) & 0xFFFF);
            }
    }
    __syncthreads();

    // --- Phase D: out = x + W3 . h2, M=256 K=128, n=16 ----------------------
    {
        f32x4 acc[4];
#pragma unroll
        for (int i = 0; i < 4; ++i) acc[i] = (f32x4){0.f, 0.f, 0.f, 0.f};
        const ushort_t* Bt = h2T + (size_t)nblk * 128;
        for (int k0 = 0; k0 < 128; k0 += 32) {
            bf16x8 bfr = *(const bf16x8*)&Bt[(size_t)l15 * 128 + k0 + lhi * 8];
#pragma unroll
            for (int mf = 0; mf < 4; ++mf) {
                const float* ap = W3 + (size_t)(w * 64 + mf * 16 + l15) * 128 + k0 + lhi * 8;
                float4 a0 = *(const float4*)ap;
                float4 a1 = *(const float4*)(ap + 4);
                bf16x8 af;
                unsigned* tp = (unsigned*)&af;
                tp[0] = cvt_pk(a0.x, a0.y); tp[1] = cvt_pk(a0.z, a0.w);
                tp[2] = cvt_pk(a1.x, a1.y); tp[3] = cvt_pk(a1.z, a1.w);
                acc[mf] = __builtin_amdgcn_mfma_f32_16x16x32_bf16(af, bfr, acc[mf], 0, 0, 0);
            }
        }
#pragma unroll
        for (int mf = 0; mf < 4; ++mf)
#pragma unroll
            for (int r = 0; r < 4; ++r) {
                int m = w * 64 + mf * 16 + lhi * 4 + r;
                float bi = b3[m];
                int n = nblk + l15;
                out[(size_t)m * NPTS + n] = acc[mf][r] + bi + x[(size_t)m * NPTS + n];
            }
    }
}

// ---------------------------------------------------------------------------
extern "C" void kernel_launch(void* const* d_in, const int* in_sizes, int n_in,
                              void* d_out, int out_size, void* d_ws, size_t ws_size,
                              hipStream_t stream) {
    const float* x  = (const float*)d_in[0];
    const float* S  = (const float*)d_in[1];
    const float* Wq = (const float*)d_in[2];
    const float* bq = (const float*)d_in[3];
    const float* Wk = (const float*)d_in[4];
    const float* bk = (const float*)d_in[5];
    const float* Wv = (const float*)d_in[6];
    const float* bv = (const float*)d_in[7];
    const float* W1 = (const float*)d_in[8];
    const float* b1 = (const float*)d_in[9];
    const float* g1 = (const float*)d_in[10];
    const float* be1= (const float*)d_in[11];
    const float* W2 = (const float*)d_in[12];
    const float* b2 = (const float*)d_in[13];
    const float* g2 = (const float*)d_in[14];
    const float* be2= (const float*)d_in[15];
    const float* W3 = (const float*)d_in[16];
    const float* b3 = (const float*)d_in[17];

    char* ws = (char*)d_ws;
    const size_t MB = 1024 * 1024;
    ushort_t* Qf   = (ushort_t*)(ws + 2 * MB);               // 2 MB
    ushort_t* Kf   = (ushort_t*)(ws + 4 * MB);               // 2 MB
    ushort_t* Vf   = (ushort_t*)(ws + 6 * MB);               // 2 MB
    ushort_t* pacc = (ushort_t*)(ws + 8 * MB);               // 16 MB
    float*    pl   = (float*)   (ws + 24 * MB);              // 512 KB
    ushort_t* msgT = (ushort_t*)(ws + 25 * MB);              // 2 MB
    ushort_t* h1T  = (ushort_t*)(ws + 27 * MB);              // 1 MB
    ushort_t* h2T  = (ushort_t*)(ws + 28 * MB);              // 1 MB

    gemm_qkv<<<dim3(64, 4, 3), 256, 0, stream>>>(Wq, bq, Wk, bk, Wv, bv, x, Qf, Kf, Vf);

    attn_mfma<<<dim3(32, NHEAD, KSPLIT), 256, 0, stream>>>(Qf, Kf, Vf, S, pacc, pl);

    mlp_fused<<<dim3(256), 256, 0, stream>>>(pacc, pl, msgT,
        W1, b1, g1, be1, W2, b2, g2, be2, W3, b3, x, (float*)d_out, h1T, h2T);
}